// Round 1
// baseline (970.531 us; speedup 1.0000x reference)
//
#include <hip/hip_runtime.h>
#include <math.h>

__device__ __forceinline__ float lrelu(float x){ return x > 0.f ? x : 0.2f * x; }

__global__ void count_deg_kernel(const int* __restrict__ dst, int E, int* __restrict__ deg){
  int e = blockIdx.x * blockDim.x + threadIdx.x;
  if (e < E) atomicAdd(&deg[dst[e]], 1);
}

__global__ void scan1_kernel(const int* __restrict__ deg, int n,
                             int* __restrict__ startv, int* __restrict__ bsum){
  __shared__ int sh[256];
  int t = threadIdx.x;
  int i = blockIdx.x * 256 + t;
  int v = (i < n) ? deg[i] : 0;
  sh[t] = v; __syncthreads();
  for (int off = 1; off < 256; off <<= 1){
    int x = (t >= off) ? sh[t - off] : 0;
    __syncthreads();
    sh[t] += x;
    __syncthreads();
  }
  if (i < n) startv[i] = sh[t] - v;          // exclusive local prefix
  if (t == 255) bsum[blockIdx.x] = sh[255];  // block total
}

__global__ void scan2_kernel(int* __restrict__ bsum, int nb){
  __shared__ int sh[1024];
  __shared__ int carry_s;
  int t = threadIdx.x;
  if (t == 0) carry_s = 0;
  __syncthreads();
  for (int base = 0; base < nb; base += 1024){
    int idx = base + t;
    int v = (idx < nb) ? bsum[idx] : 0;
    sh[t] = v; __syncthreads();
    for (int off = 1; off < 1024; off <<= 1){
      int x = (t >= off) ? sh[t - off] : 0;
      __syncthreads();
      sh[t] += x;
      __syncthreads();
    }
    int carry = carry_s;
    if (idx < nb) bsum[idx] = sh[t] - v + carry;  // exclusive across all
    __syncthreads();
    if (t == 0) carry_s = carry + sh[1023];
    __syncthreads();
  }
}

__global__ void scan3_kernel(int* __restrict__ startv, int n, const int* __restrict__ bsum){
  int i = blockIdx.x * 256 + threadIdx.x;
  if (i < n) startv[i] += bsum[blockIdx.x];
}

__global__ void fill_csr_kernel(const int* __restrict__ src, const int* __restrict__ dst, int E,
                                const int* __restrict__ startv, int* __restrict__ fillc,
                                int* __restrict__ csr_src){
  int e = blockIdx.x * blockDim.x + threadIdx.x;
  if (e >= E) return;
  int d = dst[e];
  int slot = startv[d] + atomicAdd(&fillc[d], 1);
  csr_src[slot] = src[e];
}

// f = h @ W  (32x32), el/er = per-head dot with al/ar. One thread per node.
__global__ __launch_bounds__(256) void fc_kernel(
    const float* __restrict__ hin, const int* __restrict__ nid,
    const float* __restrict__ W, const float* __restrict__ al, const float* __restrict__ ar,
    int n, float* __restrict__ f, float* __restrict__ el, float* __restrict__ er)
{
  __shared__ __align__(16) float Ws[1024];
  __shared__ float als[32], ars[32];
  int t = threadIdx.x;
  for (int i = t; i < 1024; i += 256) Ws[i] = W[i];
  if (t < 32){ als[t] = al[t]; ars[t] = ar[t]; }
  __syncthreads();
  int i = blockIdx.x * 256 + t;
  if (i >= n) return;
  long row = nid ? (long)nid[i] : (long)i;
  const float4* hp = (const float4*)(hin + row * 32);
  float h[32];
  #pragma unroll
  for (int q = 0; q < 8; ++q){
    float4 v = hp[q];
    h[4*q+0] = v.x; h[4*q+1] = v.y; h[4*q+2] = v.z; h[4*q+3] = v.w;
  }
  float fv[32];
  #pragma unroll
  for (int j = 0; j < 32; j += 4){
    float ax = 0.f, ay = 0.f, az = 0.f, aw = 0.f;
    #pragma unroll
    for (int k = 0; k < 32; ++k){
      float hk = h[k];
      float4 w = *(const float4*)&Ws[k*32 + j];
      ax += hk * w.x; ay += hk * w.y; az += hk * w.z; aw += hk * w.w;
    }
    fv[j] = ax; fv[j+1] = ay; fv[j+2] = az; fv[j+3] = aw;
  }
  float4* fp = (float4*)(f + (size_t)i * 32);
  #pragma unroll
  for (int q = 0; q < 8; ++q)
    fp[q] = make_float4(fv[4*q], fv[4*q+1], fv[4*q+2], fv[4*q+3]);
  float elv[4], erv[4];
  #pragma unroll
  for (int hh = 0; hh < 4; ++hh){
    float a = 0.f, b = 0.f;
    #pragma unroll
    for (int d = 0; d < 8; ++d){
      a += fv[hh*8 + d] * als[hh*8 + d];
      b += fv[hh*8 + d] * ars[hh*8 + d];
    }
    elv[hh] = a; erv[hh] = b;
  }
  *(float4*)(el + (size_t)i * 4) = make_float4(elv[0], elv[1], elv[2], elv[3]);
  *(float4*)(er + (size_t)i * 4) = make_float4(erv[0], erv[1], erv[2], erv[3]);
}

// One wave per dst node: max -> sum(exp) -> weighted gather-sum. Bias+ReLU epilogue.
__global__ __launch_bounds__(256) void gat_agg_kernel(
    const int* __restrict__ csr_src, const int* __restrict__ startv, const int* __restrict__ deg,
    const float* __restrict__ f, const float* __restrict__ el, const float* __restrict__ er,
    const float* __restrict__ bias, int n, float* __restrict__ hout)
{
  int wid  = threadIdx.x >> 6;
  int lane = threadIdx.x & 63;
  int v = blockIdx.x * 4 + wid;
  if (v >= n) return;
  int s = startv[v];
  int d = deg[v];
  float4 er4 = *(const float4*)(er + (size_t)v * 4);

  float m0 = -1e30f, m1 = -1e30f, m2 = -1e30f, m3 = -1e30f;
  for (int i = lane; i < d; i += 64){
    int u = csr_src[s + i];
    float4 e4 = *(const float4*)(el + (size_t)u * 4);
    m0 = fmaxf(m0, lrelu(e4.x + er4.x));
    m1 = fmaxf(m1, lrelu(e4.y + er4.y));
    m2 = fmaxf(m2, lrelu(e4.z + er4.z));
    m3 = fmaxf(m3, lrelu(e4.w + er4.w));
  }
  #pragma unroll
  for (int off = 32; off >= 1; off >>= 1){
    m0 = fmaxf(m0, __shfl_xor(m0, off));
    m1 = fmaxf(m1, __shfl_xor(m1, off));
    m2 = fmaxf(m2, __shfl_xor(m2, off));
    m3 = fmaxf(m3, __shfl_xor(m3, off));
  }
  float s0 = 0.f, s1 = 0.f, s2 = 0.f, s3 = 0.f;
  for (int i = lane; i < d; i += 64){
    int u = csr_src[s + i];
    float4 e4 = *(const float4*)(el + (size_t)u * 4);
    s0 += expf(lrelu(e4.x + er4.x) - m0);
    s1 += expf(lrelu(e4.y + er4.y) - m1);
    s2 += expf(lrelu(e4.z + er4.z) - m2);
    s3 += expf(lrelu(e4.w + er4.w) - m3);
  }
  #pragma unroll
  for (int off = 32; off >= 1; off >>= 1){
    s0 += __shfl_xor(s0, off);
    s1 += __shfl_xor(s1, off);
    s2 += __shfl_xor(s2, off);
    s3 += __shfl_xor(s3, off);
  }
  float r0 = 1.f / s0, r1 = 1.f / s1, r2 = 1.f / s2, r3 = 1.f / s3;

  int col  = lane & 31;
  int half = lane >> 5;
  int head = col >> 3;
  float me  = head == 0 ? m0 : head == 1 ? m1 : head == 2 ? m2 : m3;
  float re  = head == 0 ? r0 : head == 1 ? r1 : head == 2 ? r2 : r3;
  float ere = head == 0 ? er4.x : head == 1 ? er4.y : head == 2 ? er4.z : er4.w;

  float acc = 0.f;
  for (int i = half; i < d; i += 2){
    int u = csr_src[s + i];
    float e = lrelu(el[(size_t)u * 4 + head] + ere);
    float alpha = expf(e - me) * re;
    acc += alpha * f[(size_t)u * 32 + col];
  }
  acc += __shfl_xor(acc, 32);
  if (lane < 32){
    float o = acc + bias[col];
    hout[(size_t)v * 32 + col] = fmaxf(o, 0.f);
  }
}

__device__ int lower_bound_dev(const int* a, int n, int key){
  int lo = 0, hi = n;
  while (lo < hi){
    int mid = (lo + hi) >> 1;
    if (a[mid] < key) lo = mid + 1; else hi = mid;
  }
  return lo;
}

__global__ void pool_kernel(const float* __restrict__ hout, const int* __restrict__ gid,
                            int n, float* __restrict__ hg){
  __shared__ int lohi[2];
  int g = blockIdx.x;
  int t = threadIdx.x;
  if (t < 2) lohi[t] = lower_bound_dev(gid, n, g + t);
  __syncthreads();
  int lo = lohi[0], hi = lohi[1];
  int cnt = hi - lo;
  int col = t & 31, r0 = t >> 5;
  float acc = 0.f;
  for (int r = r0; r < cnt; r += 8)
    acc += hout[(size_t)(lo + r) * 32 + col];
  __shared__ float red[256];
  red[t] = acc; __syncthreads();
  if (t < 128) red[t] += red[t + 128];
  __syncthreads();
  if (t < 64) red[t] += red[t + 64];
  __syncthreads();
  if (t < 32){
    float sum = red[t] + red[t + 32];
    hg[g * 32 + t] = sum / fmaxf((float)cnt, 1.f);
  }
}

__global__ void score_kernel(const float* __restrict__ hg, const float* __restrict__ sw1,
                             const float* __restrict__ sb1, const float* __restrict__ sw2,
                             const float* __restrict__ sb2, int B, float* __restrict__ out){
  int g = blockIdx.x * blockDim.x + threadIdx.x;
  if (g >= B) return;
  float hvec[32];
  const float4* hp = (const float4*)(hg + g * 32);
  #pragma unroll
  for (int q = 0; q < 8; ++q){
    float4 v = hp[q];
    hvec[4*q+0] = v.x; hvec[4*q+1] = v.y; hvec[4*q+2] = v.z; hvec[4*q+3] = v.w;
  }
  float o = sb2[0];
  #pragma unroll
  for (int j = 0; j < 32; ++j){
    float a = sb1[j];
    #pragma unroll
    for (int k = 0; k < 32; ++k) a += hvec[k] * sw1[k*32 + j];
    o += fmaxf(a, 0.f) * sw2[j];
  }
  out[g] = o;
}

extern "C" void kernel_launch(void* const* d_in, const int* in_sizes, int n_in,
                              void* d_out, int out_size, void* d_ws, size_t ws_size,
                              hipStream_t stream)
{
  const int*   node_ids = (const int*)d_in[0];
  const int*   srcp     = (const int*)d_in[1];
  const int*   dstp     = (const int*)d_in[2];
  const int*   gid      = (const int*)d_in[3];
  const float* emb      = (const float*)d_in[4];
  const float* W0       = (const float*)d_in[5];
  const float* al0      = (const float*)d_in[6];
  const float* ar0      = (const float*)d_in[7];
  const float* b0       = (const float*)d_in[8];
  const float* W1       = (const float*)d_in[9];
  const float* al1      = (const float*)d_in[10];
  const float* ar1      = (const float*)d_in[11];
  const float* b1       = (const float*)d_in[12];
  const float* sw1      = (const float*)d_in[13];
  const float* sb1      = (const float*)d_in[14];
  const float* sw2      = (const float*)d_in[15];
  const float* sb2      = (const float*)d_in[16];

  int N = in_sizes[0];
  int E = in_sizes[1];
  int B = out_size;           // output is [B,1] float32
  float* out = (float*)d_out;

  // Workspace carve-out (256B aligned)
  char* p = (char*)d_ws;
  auto alloc = [&](size_t bytes) -> char* {
    char* r = p;
    p += (bytes + 255) & ~(size_t)255;
    return r;
  };
  int nb = (N + 255) / 256;
  int*   deg     = (int*)alloc((size_t)N * 4);
  int*   startv  = (int*)alloc((size_t)N * 4);
  int*   fillc   = (int*)alloc((size_t)N * 4);
  int*   bsum    = (int*)alloc((size_t)nb * 4);
  int*   csr_src = (int*)alloc((size_t)E * 4);
  float* el      = (float*)alloc((size_t)N * 16);
  float* er      = (float*)alloc((size_t)N * 16);
  float* f       = (float*)alloc((size_t)N * 128);
  float* h       = (float*)alloc((size_t)N * 128);
  float* hg      = (float*)alloc((size_t)B * 32 * 4);

  hipMemsetAsync(deg,   0, (size_t)N * 4, stream);
  hipMemsetAsync(fillc, 0, (size_t)N * 4, stream);

  int eb = (E + 255) / 256;
  count_deg_kernel<<<eb, 256, 0, stream>>>(dstp, E, deg);
  scan1_kernel<<<nb, 256, 0, stream>>>(deg, N, startv, bsum);
  scan2_kernel<<<1, 1024, 0, stream>>>(bsum, nb);
  scan3_kernel<<<nb, 256, 0, stream>>>(startv, N, bsum);
  fill_csr_kernel<<<eb, 256, 0, stream>>>(srcp, dstp, E, startv, fillc, csr_src);

  int nblk = (N + 255) / 256;
  int ablk = (N + 3) / 4;
  // Layer 0: h_in = emb[node_ids]
  fc_kernel<<<nblk, 256, 0, stream>>>(emb, node_ids, W0, al0, ar0, N, f, el, er);
  gat_agg_kernel<<<ablk, 256, 0, stream>>>(csr_src, startv, deg, f, el, er, b0, N, h);
  // Layer 1: h_in = h
  fc_kernel<<<nblk, 256, 0, stream>>>(h, nullptr, W1, al1, ar1, N, f, el, er);
  gat_agg_kernel<<<ablk, 256, 0, stream>>>(csr_src, startv, deg, f, el, er, b1, N, h);

  pool_kernel<<<B, 256, 0, stream>>>(h, gid, N, hg);
  score_kernel<<<(B + 63) / 64, 64, 0, stream>>>(hg, sw1, sb1, sw2, sb2, B, out);
}

// Round 2
// 826.184 us; speedup vs baseline: 1.1747x; 1.1747x over previous
//
#include <hip/hip_runtime.h>
#include <math.h>

__device__ __forceinline__ float lrelu(float x){ return x > 0.f ? x : 0.2f * x; }

__global__ void count_deg_kernel(const int* __restrict__ dst, int E, int* __restrict__ deg){
  int e = blockIdx.x * blockDim.x + threadIdx.x;
  if (e < E) atomicAdd(&deg[dst[e]], 1);
}

__global__ void scan1_kernel(const int* __restrict__ deg, int n,
                             int* __restrict__ startv, int* __restrict__ bsum){
  __shared__ int sh[256];
  int t = threadIdx.x;
  int i = blockIdx.x * 256 + t;
  int v = (i < n) ? deg[i] : 0;
  sh[t] = v; __syncthreads();
  for (int off = 1; off < 256; off <<= 1){
    int x = (t >= off) ? sh[t - off] : 0;
    __syncthreads();
    sh[t] += x;
    __syncthreads();
  }
  if (i < n) startv[i] = sh[t] - v;          // exclusive local prefix
  if (t == 255) bsum[blockIdx.x] = sh[255];  // block total
}

__global__ void scan2_kernel(int* __restrict__ bsum, int nb){
  __shared__ int sh[1024];
  __shared__ int carry_s;
  int t = threadIdx.x;
  if (t == 0) carry_s = 0;
  __syncthreads();
  for (int base = 0; base < nb; base += 1024){
    int idx = base + t;
    int v = (idx < nb) ? bsum[idx] : 0;
    sh[t] = v; __syncthreads();
    for (int off = 1; off < 1024; off <<= 1){
      int x = (t >= off) ? sh[t - off] : 0;
      __syncthreads();
      sh[t] += x;
      __syncthreads();
    }
    int carry = carry_s;
    if (idx < nb) bsum[idx] = sh[t] - v + carry;  // exclusive across all
    __syncthreads();
    if (t == 0) carry_s = carry + sh[1023];
    __syncthreads();
  }
}

__global__ void scan3_kernel(int* __restrict__ startv, int n, const int* __restrict__ bsum){
  int i = blockIdx.x * 256 + threadIdx.x;
  if (i < n) startv[i] += bsum[blockIdx.x];
}

__global__ void fill_csr_kernel(const int* __restrict__ src, const int* __restrict__ dst, int E,
                                const int* __restrict__ startv, int* __restrict__ fillc,
                                int* __restrict__ csr_src){
  int e = blockIdx.x * blockDim.x + threadIdx.x;
  if (e >= E) return;
  int d = dst[e];
  int slot = startv[d] + atomicAdd(&fillc[d], 1);
  csr_src[slot] = src[e];
}

// f = h @ W  (32x32), el/er = per-head dot with al/ar. One thread per node.
__global__ __launch_bounds__(256) void fc_kernel(
    const float* __restrict__ hin, const int* __restrict__ nid,
    const float* __restrict__ W, const float* __restrict__ al, const float* __restrict__ ar,
    int n, float* __restrict__ f, float* __restrict__ el, float* __restrict__ er)
{
  __shared__ __align__(16) float Ws[1024];
  __shared__ float als[32], ars[32];
  int t = threadIdx.x;
  for (int i = t; i < 1024; i += 256) Ws[i] = W[i];
  if (t < 32){ als[t] = al[t]; ars[t] = ar[t]; }
  __syncthreads();
  int i = blockIdx.x * 256 + t;
  if (i >= n) return;
  long row = nid ? (long)nid[i] : (long)i;
  const float4* hp = (const float4*)(hin + row * 32);
  float h[32];
  #pragma unroll
  for (int q = 0; q < 8; ++q){
    float4 v = hp[q];
    h[4*q+0] = v.x; h[4*q+1] = v.y; h[4*q+2] = v.z; h[4*q+3] = v.w;
  }
  float fv[32];
  #pragma unroll
  for (int j = 0; j < 32; j += 4){
    float ax = 0.f, ay = 0.f, az = 0.f, aw = 0.f;
    #pragma unroll
    for (int k = 0; k < 32; ++k){
      float hk = h[k];
      float4 w = *(const float4*)&Ws[k*32 + j];
      ax += hk * w.x; ay += hk * w.y; az += hk * w.z; aw += hk * w.w;
    }
    fv[j] = ax; fv[j+1] = ay; fv[j+2] = az; fv[j+3] = aw;
  }
  float4* fp = (float4*)(f + (size_t)i * 32);
  #pragma unroll
  for (int q = 0; q < 8; ++q)
    fp[q] = make_float4(fv[4*q], fv[4*q+1], fv[4*q+2], fv[4*q+3]);
  float elv[4], erv[4];
  #pragma unroll
  for (int hh = 0; hh < 4; ++hh){
    float a = 0.f, b = 0.f;
    #pragma unroll
    for (int d = 0; d < 8; ++d){
      a += fv[hh*8 + d] * als[hh*8 + d];
      b += fv[hh*8 + d] * ars[hh*8 + d];
    }
    elv[hh] = a; erv[hh] = b;
  }
  *(float4*)(el + (size_t)i * 4) = make_float4(elv[0], elv[1], elv[2], elv[3]);
  *(float4*)(er + (size_t)i * 4) = make_float4(erv[0], erv[1], erv[2], erv[3]);
}

// One wave per dst node. Fast path (deg<=64): cache edge list + normalized
// attention weights in LDS, single gather pass. Slow path: 3-pass recompute.
__global__ __launch_bounds__(256) void gat_agg_kernel(
    const int* __restrict__ csr_src, const int* __restrict__ startv, const int* __restrict__ deg,
    const float* __restrict__ f, const float* __restrict__ el, const float* __restrict__ er,
    const float* __restrict__ bias, int n, float* __restrict__ hout)
{
  __shared__ int    su_s[4][64];
  __shared__ float4 ex_s[4][64];
  int wid  = threadIdx.x >> 6;
  int lane = threadIdx.x & 63;
  int v = blockIdx.x * 4 + wid;
  if (v >= n) return;
  int s = startv[v];
  int d = deg[v];
  float4 er4 = *(const float4*)(er + (size_t)v * 4);
  int col  = lane & 31;
  int half = lane >> 5;
  int head = col >> 3;
  float acc = 0.f;

  if (d > 0 && d <= 64){
    int*    suw = su_s[wid];
    float4* exw = ex_s[wid];
    float e0 = -1e30f, e1 = -1e30f, e2 = -1e30f, e3 = -1e30f;
    if (lane < d){
      int u = csr_src[s + lane];
      suw[lane] = u;
      float4 l4 = *(const float4*)(el + (size_t)u * 4);
      e0 = lrelu(l4.x + er4.x);
      e1 = lrelu(l4.y + er4.y);
      e2 = lrelu(l4.z + er4.z);
      e3 = lrelu(l4.w + er4.w);
    }
    float m0 = e0, m1 = e1, m2 = e2, m3 = e3;
    #pragma unroll
    for (int off = 32; off >= 1; off >>= 1){
      m0 = fmaxf(m0, __shfl_xor(m0, off));
      m1 = fmaxf(m1, __shfl_xor(m1, off));
      m2 = fmaxf(m2, __shfl_xor(m2, off));
      m3 = fmaxf(m3, __shfl_xor(m3, off));
    }
    float x0 = 0.f, x1 = 0.f, x2 = 0.f, x3 = 0.f;
    if (lane < d){
      x0 = expf(e0 - m0); x1 = expf(e1 - m1);
      x2 = expf(e2 - m2); x3 = expf(e3 - m3);
    }
    float s0 = x0, s1 = x1, s2 = x2, s3 = x3;
    #pragma unroll
    for (int off = 32; off >= 1; off >>= 1){
      s0 += __shfl_xor(s0, off);
      s1 += __shfl_xor(s1, off);
      s2 += __shfl_xor(s2, off);
      s3 += __shfl_xor(s3, off);
    }
    if (lane < d)
      exw[lane] = make_float4(x0 / s0, x1 / s1, x2 / s2, x3 / s3);
    // DS ops of a wave complete in order; block the compiler from reordering
    // and drain LDS before cross-lane reads. Wave-local: no block barrier.
    asm volatile("s_waitcnt lgkmcnt(0)" ::: "memory");
    const float* exf = (const float*)exw;
    for (int i = half; i < d; i += 2){
      int u = suw[i];
      float a = exf[i * 4 + head];
      acc = fmaf(a, f[(size_t)u * 32 + col], acc);
    }
  } else if (d > 64){
    // slow path: 3-pass global recompute (statistically never for Poisson(16))
    float m0 = -1e30f, m1 = -1e30f, m2 = -1e30f, m3 = -1e30f;
    for (int i = lane; i < d; i += 64){
      int u = csr_src[s + i];
      float4 e4 = *(const float4*)(el + (size_t)u * 4);
      m0 = fmaxf(m0, lrelu(e4.x + er4.x));
      m1 = fmaxf(m1, lrelu(e4.y + er4.y));
      m2 = fmaxf(m2, lrelu(e4.z + er4.z));
      m3 = fmaxf(m3, lrelu(e4.w + er4.w));
    }
    #pragma unroll
    for (int off = 32; off >= 1; off >>= 1){
      m0 = fmaxf(m0, __shfl_xor(m0, off));
      m1 = fmaxf(m1, __shfl_xor(m1, off));
      m2 = fmaxf(m2, __shfl_xor(m2, off));
      m3 = fmaxf(m3, __shfl_xor(m3, off));
    }
    float s0 = 0.f, s1 = 0.f, s2 = 0.f, s3 = 0.f;
    for (int i = lane; i < d; i += 64){
      int u = csr_src[s + i];
      float4 e4 = *(const float4*)(el + (size_t)u * 4);
      s0 += expf(lrelu(e4.x + er4.x) - m0);
      s1 += expf(lrelu(e4.y + er4.y) - m1);
      s2 += expf(lrelu(e4.z + er4.z) - m2);
      s3 += expf(lrelu(e4.w + er4.w) - m3);
    }
    #pragma unroll
    for (int off = 32; off >= 1; off >>= 1){
      s0 += __shfl_xor(s0, off);
      s1 += __shfl_xor(s1, off);
      s2 += __shfl_xor(s2, off);
      s3 += __shfl_xor(s3, off);
    }
    float me  = head == 0 ? m0 : head == 1 ? m1 : head == 2 ? m2 : m3;
    float se  = head == 0 ? s0 : head == 1 ? s1 : head == 2 ? s2 : s3;
    float re  = 1.f / se;
    float ere = head == 0 ? er4.x : head == 1 ? er4.y : head == 2 ? er4.z : er4.w;
    for (int i = half; i < d; i += 2){
      int u = csr_src[s + i];
      float e = lrelu(el[(size_t)u * 4 + head] + ere);
      float alpha = expf(e - me) * re;
      acc = fmaf(alpha, f[(size_t)u * 32 + col], acc);
    }
  }

  acc += __shfl_xor(acc, 32);
  if (lane < 32){
    float o = acc + bias[col];
    hout[(size_t)v * 32 + col] = fmaxf(o, 0.f);
  }
}

__device__ int lower_bound_dev(const int* a, int n, int key){
  int lo = 0, hi = n;
  while (lo < hi){
    int mid = (lo + hi) >> 1;
    if (a[mid] < key) lo = mid + 1; else hi = mid;
  }
  return lo;
}

__global__ void pool_kernel(const float* __restrict__ hout, const int* __restrict__ gid,
                            int n, float* __restrict__ hg){
  __shared__ int lohi[2];
  int g = blockIdx.x;
  int t = threadIdx.x;
  if (t < 2) lohi[t] = lower_bound_dev(gid, n, g + t);
  __syncthreads();
  int lo = lohi[0], hi = lohi[1];
  int cnt = hi - lo;
  int col = t & 31, r0 = t >> 5;
  float acc = 0.f;
  for (int r = r0; r < cnt; r += 8)
    acc += hout[(size_t)(lo + r) * 32 + col];
  __shared__ float red[256];
  red[t] = acc; __syncthreads();
  if (t < 128) red[t] += red[t + 128];
  __syncthreads();
  if (t < 64) red[t] += red[t + 64];
  __syncthreads();
  if (t < 32){
    float sum = red[t] + red[t + 32];
    hg[g * 32 + t] = sum / fmaxf((float)cnt, 1.f);
  }
}

__global__ void score_kernel(const float* __restrict__ hg, const float* __restrict__ sw1,
                             const float* __restrict__ sb1, const float* __restrict__ sw2,
                             const float* __restrict__ sb2, int B, float* __restrict__ out){
  int g = blockIdx.x * blockDim.x + threadIdx.x;
  if (g >= B) return;
  float hvec[32];
  const float4* hp = (const float4*)(hg + g * 32);
  #pragma unroll
  for (int q = 0; q < 8; ++q){
    float4 v = hp[q];
    hvec[4*q+0] = v.x; hvec[4*q+1] = v.y; hvec[4*q+2] = v.z; hvec[4*q+3] = v.w;
  }
  float o = sb2[0];
  #pragma unroll
  for (int j = 0; j < 32; ++j){
    float a = sb1[j];
    #pragma unroll
    for (int k = 0; k < 32; ++k) a += hvec[k] * sw1[k*32 + j];
    o += fmaxf(a, 0.f) * sw2[j];
  }
  out[g] = o;
}

extern "C" void kernel_launch(void* const* d_in, const int* in_sizes, int n_in,
                              void* d_out, int out_size, void* d_ws, size_t ws_size,
                              hipStream_t stream)
{
  const int*   node_ids = (const int*)d_in[0];
  const int*   srcp     = (const int*)d_in[1];
  const int*   dstp     = (const int*)d_in[2];
  const int*   gid      = (const int*)d_in[3];
  const float* emb      = (const float*)d_in[4];
  const float* W0       = (const float*)d_in[5];
  const float* al0      = (const float*)d_in[6];
  const float* ar0      = (const float*)d_in[7];
  const float* b0       = (const float*)d_in[8];
  const float* W1       = (const float*)d_in[9];
  const float* al1      = (const float*)d_in[10];
  const float* ar1      = (const float*)d_in[11];
  const float* b1       = (const float*)d_in[12];
  const float* sw1      = (const float*)d_in[13];
  const float* sb1      = (const float*)d_in[14];
  const float* sw2      = (const float*)d_in[15];
  const float* sb2      = (const float*)d_in[16];

  int N = in_sizes[0];
  int E = in_sizes[1];
  int B = out_size;           // output is [B,1] float32
  float* out = (float*)d_out;

  // Workspace carve-out (256B aligned)
  char* p = (char*)d_ws;
  auto alloc = [&](size_t bytes) -> char* {
    char* r = p;
    p += (bytes + 255) & ~(size_t)255;
    return r;
  };
  int nb = (N + 255) / 256;
  int*   deg     = (int*)alloc((size_t)N * 4);
  int*   startv  = (int*)alloc((size_t)N * 4);
  int*   fillc   = (int*)alloc((size_t)N * 4);
  int*   bsum    = (int*)alloc((size_t)nb * 4);
  int*   csr_src = (int*)alloc((size_t)E * 4);
  float* el      = (float*)alloc((size_t)N * 16);
  float* er      = (float*)alloc((size_t)N * 16);
  float* f       = (float*)alloc((size_t)N * 128);
  float* h       = (float*)alloc((size_t)N * 128);
  float* hg      = (float*)alloc((size_t)B * 32 * 4);

  hipMemsetAsync(deg,   0, (size_t)N * 4, stream);
  hipMemsetAsync(fillc, 0, (size_t)N * 4, stream);

  int eb = (E + 255) / 256;
  count_deg_kernel<<<eb, 256, 0, stream>>>(dstp, E, deg);
  scan1_kernel<<<nb, 256, 0, stream>>>(deg, N, startv, bsum);
  scan2_kernel<<<1, 1024, 0, stream>>>(bsum, nb);
  scan3_kernel<<<nb, 256, 0, stream>>>(startv, N, bsum);
  fill_csr_kernel<<<eb, 256, 0, stream>>>(srcp, dstp, E, startv, fillc, csr_src);

  int nblk = (N + 255) / 256;
  int ablk = (N + 3) / 4;
  // Layer 0: h_in = emb[node_ids]
  fc_kernel<<<nblk, 256, 0, stream>>>(emb, node_ids, W0, al0, ar0, N, f, el, er);
  gat_agg_kernel<<<ablk, 256, 0, stream>>>(csr_src, startv, deg, f, el, er, b0, N, h);
  // Layer 1: h_in = h
  fc_kernel<<<nblk, 256, 0, stream>>>(h, nullptr, W1, al1, ar1, N, f, el, er);
  gat_agg_kernel<<<ablk, 256, 0, stream>>>(csr_src, startv, deg, f, el, er, b1, N, h);

  pool_kernel<<<B, 256, 0, stream>>>(h, gid, N, hg);
  score_kernel<<<(B + 63) / 64, 64, 0, stream>>>(hg, sw1, sb1, sw2, sb2, B, out);
}

// Round 3
// 789.349 us; speedup vs baseline: 1.2295x; 1.0467x over previous
//
#include <hip/hip_runtime.h>
#include <math.h>

__device__ __forceinline__ float lrelu(float x){ return x > 0.f ? x : 0.2f * x; }

__global__ void count_deg_kernel(const int* __restrict__ dst, int E, int* __restrict__ deg){
  int e = blockIdx.x * blockDim.x + threadIdx.x;
  if (e < E) atomicAdd(&deg[dst[e]], 1);
}

__global__ void scan1_kernel(const int* __restrict__ deg, int n,
                             int* __restrict__ startv, int* __restrict__ bsum){
  __shared__ int sh[256];
  int t = threadIdx.x;
  int i = blockIdx.x * 256 + t;
  int v = (i < n) ? deg[i] : 0;
  sh[t] = v; __syncthreads();
  for (int off = 1; off < 256; off <<= 1){
    int x = (t >= off) ? sh[t - off] : 0;
    __syncthreads();
    sh[t] += x;
    __syncthreads();
  }
  if (i < n) startv[i] = sh[t] - v;          // exclusive local prefix
  if (t == 255) bsum[blockIdx.x] = sh[255];  // block total
}

__global__ void scan2_kernel(int* __restrict__ bsum, int nb){
  __shared__ int sh[1024];
  __shared__ int carry_s;
  int t = threadIdx.x;
  if (t == 0) carry_s = 0;
  __syncthreads();
  for (int base = 0; base < nb; base += 1024){
    int idx = base + t;
    int v = (idx < nb) ? bsum[idx] : 0;
    sh[t] = v; __syncthreads();
    for (int off = 1; off < 1024; off <<= 1){
      int x = (t >= off) ? sh[t - off] : 0;
      __syncthreads();
      sh[t] += x;
      __syncthreads();
    }
    int carry = carry_s;
    if (idx < nb) bsum[idx] = sh[t] - v + carry;  // exclusive across all
    __syncthreads();
    if (t == 0) carry_s = carry + sh[1023];
    __syncthreads();
  }
}

__global__ void scan3_kernel(int* __restrict__ startv, int n, const int* __restrict__ bsum){
  int i = blockIdx.x * 256 + threadIdx.x;
  if (i < n) startv[i] += bsum[blockIdx.x];
}

// gcur[b] = edge-region start of bucket b (free from the node-level scan)
__global__ void init_gcur_kernel(const int* __restrict__ startv, int n, int shift, int nbk,
                                 int* __restrict__ gcur){
  int b = blockIdx.x * blockDim.x + threadIdx.x;
  if (b < nbk) gcur[b] = startv[b << shift];
}

// Bin edges by coarse dst-bucket so the CSR fill has write locality.
// 4096 edges per block; LDS histogram + LDS rank; one global atomic per (block,bucket).
__global__ __launch_bounds__(256) void bin_kernel(
    const int* __restrict__ src, const int* __restrict__ dst, int E, int shift, int nbk,
    int* __restrict__ gcur, uint2* __restrict__ ebuf)
{
  __shared__ int hist[256];
  __shared__ int lbase[256];
  int t = threadIdx.x;
  long base = (long)blockIdx.x * 4096;
  for (int i = t; i < nbk; i += 256) hist[i] = 0;
  __syncthreads();
  int s_[16], d_[16];
  #pragma unroll
  for (int k = 0; k < 16; ++k){
    long e = base + (long)k * 256 + t;
    if (e < E){
      s_[k] = src[e]; d_[k] = dst[e];
      atomicAdd(&hist[d_[k] >> shift], 1);
    } else d_[k] = -1;
  }
  __syncthreads();
  for (int i = t; i < nbk; i += 256){
    lbase[i] = atomicAdd(&gcur[i], hist[i]);
    hist[i] = 0;
  }
  __syncthreads();
  #pragma unroll
  for (int k = 0; k < 16; ++k){
    if (d_[k] >= 0){
      int b = d_[k] >> shift;
      int r = atomicAdd(&hist[b], 1);
      ebuf[lbase[b] + r] = make_uint2((unsigned)s_[k], (unsigned)d_[k]);
    }
  }
}

// Fill CSR from bucket-ordered edges: scattered writes stay in a small moving window.
__global__ void fill_csr2_kernel(const uint2* __restrict__ ebuf, int E,
                                 const int* __restrict__ startv, int* __restrict__ fillc,
                                 int* __restrict__ csr_src){
  int e = blockIdx.x * blockDim.x + threadIdx.x;
  if (e >= E) return;
  uint2 p = ebuf[e];
  int d = (int)p.y;
  int slot = startv[d] + atomicAdd(&fillc[d], 1);
  csr_src[slot] = (int)p.x;
}

// f = h @ W  (32x32), el/er = per-head dot with al/ar. One thread per node.
__global__ __launch_bounds__(256) void fc_kernel(
    const float* __restrict__ hin, const int* __restrict__ nid,
    const float* __restrict__ W, const float* __restrict__ al, const float* __restrict__ ar,
    int n, float* __restrict__ f, float* __restrict__ el, float* __restrict__ er)
{
  __shared__ __align__(16) float Ws[1024];
  __shared__ float als[32], ars[32];
  int t = threadIdx.x;
  for (int i = t; i < 1024; i += 256) Ws[i] = W[i];
  if (t < 32){ als[t] = al[t]; ars[t] = ar[t]; }
  __syncthreads();
  int i = blockIdx.x * 256 + t;
  if (i >= n) return;
  long row = nid ? (long)nid[i] : (long)i;
  const float4* hp = (const float4*)(hin + row * 32);
  float h[32];
  #pragma unroll
  for (int q = 0; q < 8; ++q){
    float4 v = hp[q];
    h[4*q+0] = v.x; h[4*q+1] = v.y; h[4*q+2] = v.z; h[4*q+3] = v.w;
  }
  float fv[32];
  #pragma unroll
  for (int j = 0; j < 32; j += 4){
    float ax = 0.f, ay = 0.f, az = 0.f, aw = 0.f;
    #pragma unroll
    for (int k = 0; k < 32; ++k){
      float hk = h[k];
      float4 w = *(const float4*)&Ws[k*32 + j];
      ax += hk * w.x; ay += hk * w.y; az += hk * w.z; aw += hk * w.w;
    }
    fv[j] = ax; fv[j+1] = ay; fv[j+2] = az; fv[j+3] = aw;
  }
  float4* fp = (float4*)(f + (size_t)i * 32);
  #pragma unroll
  for (int q = 0; q < 8; ++q)
    fp[q] = make_float4(fv[4*q], fv[4*q+1], fv[4*q+2], fv[4*q+3]);
  float elv[4], erv[4];
  #pragma unroll
  for (int hh = 0; hh < 4; ++hh){
    float a = 0.f, b = 0.f;
    #pragma unroll
    for (int d = 0; d < 8; ++d){
      a += fv[hh*8 + d] * als[hh*8 + d];
      b += fv[hh*8 + d] * ars[hh*8 + d];
    }
    elv[hh] = a; erv[hh] = b;
  }
  *(float4*)(el + (size_t)i * 4) = make_float4(elv[0], elv[1], elv[2], elv[3]);
  *(float4*)(er + (size_t)i * 4) = make_float4(erv[0], erv[1], erv[2], erv[3]);
}

// One wave per dst node. Fast path (deg<=64): cache edge list + normalized
// attention weights in LDS, single gather pass. Slow path: 3-pass recompute.
__global__ __launch_bounds__(256) void gat_agg_kernel(
    const int* __restrict__ csr_src, const int* __restrict__ startv, const int* __restrict__ deg,
    const float* __restrict__ f, const float* __restrict__ el, const float* __restrict__ er,
    const float* __restrict__ bias, int n, float* __restrict__ hout)
{
  __shared__ int    su_s[4][64];
  __shared__ float4 ex_s[4][64];
  int wid  = threadIdx.x >> 6;
  int lane = threadIdx.x & 63;
  int v = blockIdx.x * 4 + wid;
  if (v >= n) return;
  int s = startv[v];
  int d = deg[v];
  float4 er4 = *(const float4*)(er + (size_t)v * 4);
  int col  = lane & 31;
  int half = lane >> 5;
  int head = col >> 3;
  float acc = 0.f;

  if (d > 0 && d <= 64){
    int*    suw = su_s[wid];
    float4* exw = ex_s[wid];
    float e0 = -1e30f, e1 = -1e30f, e2 = -1e30f, e3 = -1e30f;
    if (lane < d){
      int u = csr_src[s + lane];
      suw[lane] = u;
      float4 l4 = *(const float4*)(el + (size_t)u * 4);
      e0 = lrelu(l4.x + er4.x);
      e1 = lrelu(l4.y + er4.y);
      e2 = lrelu(l4.z + er4.z);
      e3 = lrelu(l4.w + er4.w);
    }
    float m0 = e0, m1 = e1, m2 = e2, m3 = e3;
    #pragma unroll
    for (int off = 32; off >= 1; off >>= 1){
      m0 = fmaxf(m0, __shfl_xor(m0, off));
      m1 = fmaxf(m1, __shfl_xor(m1, off));
      m2 = fmaxf(m2, __shfl_xor(m2, off));
      m3 = fmaxf(m3, __shfl_xor(m3, off));
    }
    float x0 = 0.f, x1 = 0.f, x2 = 0.f, x3 = 0.f;
    if (lane < d){
      x0 = expf(e0 - m0); x1 = expf(e1 - m1);
      x2 = expf(e2 - m2); x3 = expf(e3 - m3);
    }
    float s0 = x0, s1 = x1, s2 = x2, s3 = x3;
    #pragma unroll
    for (int off = 32; off >= 1; off >>= 1){
      s0 += __shfl_xor(s0, off);
      s1 += __shfl_xor(s1, off);
      s2 += __shfl_xor(s2, off);
      s3 += __shfl_xor(s3, off);
    }
    if (lane < d)
      exw[lane] = make_float4(x0 / s0, x1 / s1, x2 / s2, x3 / s3);
    // DS ops of a wave complete in order; block the compiler from reordering
    // and drain LDS before cross-lane reads. Wave-local: no block barrier.
    asm volatile("s_waitcnt lgkmcnt(0)" ::: "memory");
    const float* exf = (const float*)exw;
    for (int i = half; i < d; i += 2){
      int u = suw[i];
      float a = exf[i * 4 + head];
      acc = fmaf(a, f[(size_t)u * 32 + col], acc);
    }
  } else if (d > 64){
    // slow path: 3-pass global recompute (statistically never for Poisson(16))
    float m0 = -1e30f, m1 = -1e30f, m2 = -1e30f, m3 = -1e30f;
    for (int i = lane; i < d; i += 64){
      int u = csr_src[s + i];
      float4 e4 = *(const float4*)(el + (size_t)u * 4);
      m0 = fmaxf(m0, lrelu(e4.x + er4.x));
      m1 = fmaxf(m1, lrelu(e4.y + er4.y));
      m2 = fmaxf(m2, lrelu(e4.z + er4.z));
      m3 = fmaxf(m3, lrelu(e4.w + er4.w));
    }
    #pragma unroll
    for (int off = 32; off >= 1; off >>= 1){
      m0 = fmaxf(m0, __shfl_xor(m0, off));
      m1 = fmaxf(m1, __shfl_xor(m1, off));
      m2 = fmaxf(m2, __shfl_xor(m2, off));
      m3 = fmaxf(m3, __shfl_xor(m3, off));
    }
    float s0 = 0.f, s1 = 0.f, s2 = 0.f, s3 = 0.f;
    for (int i = lane; i < d; i += 64){
      int u = csr_src[s + i];
      float4 e4 = *(const float4*)(el + (size_t)u * 4);
      s0 += expf(lrelu(e4.x + er4.x) - m0);
      s1 += expf(lrelu(e4.y + er4.y) - m1);
      s2 += expf(lrelu(e4.z + er4.z) - m2);
      s3 += expf(lrelu(e4.w + er4.w) - m3);
    }
    #pragma unroll
    for (int off = 32; off >= 1; off >>= 1){
      s0 += __shfl_xor(s0, off);
      s1 += __shfl_xor(s1, off);
      s2 += __shfl_xor(s2, off);
      s3 += __shfl_xor(s3, off);
    }
    float me  = head == 0 ? m0 : head == 1 ? m1 : head == 2 ? m2 : m3;
    float se  = head == 0 ? s0 : head == 1 ? s1 : head == 2 ? s2 : s3;
    float re  = 1.f / se;
    float ere = head == 0 ? er4.x : head == 1 ? er4.y : head == 2 ? er4.z : er4.w;
    for (int i = half; i < d; i += 2){
      int u = csr_src[s + i];
      float e = lrelu(el[(size_t)u * 4 + head] + ere);
      float alpha = expf(e - me) * re;
      acc = fmaf(alpha, f[(size_t)u * 32 + col], acc);
    }
  }

  acc += __shfl_xor(acc, 32);
  if (lane < 32){
    float o = acc + bias[col];
    hout[(size_t)v * 32 + col] = fmaxf(o, 0.f);
  }
}

__device__ int lower_bound_dev(const int* a, int n, int key){
  int lo = 0, hi = n;
  while (lo < hi){
    int mid = (lo + hi) >> 1;
    if (a[mid] < key) lo = mid + 1; else hi = mid;
  }
  return lo;
}

__global__ void pool_kernel(const float* __restrict__ hout, const int* __restrict__ gid,
                            int n, float* __restrict__ hg){
  __shared__ int lohi[2];
  int g = blockIdx.x;
  int t = threadIdx.x;
  if (t < 2) lohi[t] = lower_bound_dev(gid, n, g + t);
  __syncthreads();
  int lo = lohi[0], hi = lohi[1];
  int cnt = hi - lo;
  int col = t & 31, r0 = t >> 5;
  float acc = 0.f;
  for (int r = r0; r < cnt; r += 8)
    acc += hout[(size_t)(lo + r) * 32 + col];
  __shared__ float red[256];
  red[t] = acc; __syncthreads();
  if (t < 128) red[t] += red[t + 128];
  __syncthreads();
  if (t < 64) red[t] += red[t + 64];
  __syncthreads();
  if (t < 32){
    float sum = red[t] + red[t + 32];
    hg[g * 32 + t] = sum / fmaxf((float)cnt, 1.f);
  }
}

__global__ void score_kernel(const float* __restrict__ hg, const float* __restrict__ sw1,
                             const float* __restrict__ sb1, const float* __restrict__ sw2,
                             const float* __restrict__ sb2, int B, float* __restrict__ out){
  int g = blockIdx.x * blockDim.x + threadIdx.x;
  if (g >= B) return;
  float hvec[32];
  const float4* hp = (const float4*)(hg + g * 32);
  #pragma unroll
  for (int q = 0; q < 8; ++q){
    float4 v = hp[q];
    hvec[4*q+0] = v.x; hvec[4*q+1] = v.y; hvec[4*q+2] = v.z; hvec[4*q+3] = v.w;
  }
  float o = sb2[0];
  #pragma unroll
  for (int j = 0; j < 32; ++j){
    float a = sb1[j];
    #pragma unroll
    for (int k = 0; k < 32; ++k) a += hvec[k] * sw1[k*32 + j];
    o += fmaxf(a, 0.f) * sw2[j];
  }
  out[g] = o;
}

extern "C" void kernel_launch(void* const* d_in, const int* in_sizes, int n_in,
                              void* d_out, int out_size, void* d_ws, size_t ws_size,
                              hipStream_t stream)
{
  const int*   node_ids = (const int*)d_in[0];
  const int*   srcp     = (const int*)d_in[1];
  const int*   dstp     = (const int*)d_in[2];
  const int*   gid      = (const int*)d_in[3];
  const float* emb      = (const float*)d_in[4];
  const float* W0       = (const float*)d_in[5];
  const float* al0      = (const float*)d_in[6];
  const float* ar0      = (const float*)d_in[7];
  const float* b0       = (const float*)d_in[8];
  const float* W1       = (const float*)d_in[9];
  const float* al1      = (const float*)d_in[10];
  const float* ar1      = (const float*)d_in[11];
  const float* b1       = (const float*)d_in[12];
  const float* sw1      = (const float*)d_in[13];
  const float* sb1      = (const float*)d_in[14];
  const float* sw2      = (const float*)d_in[15];
  const float* sb2      = (const float*)d_in[16];

  int N = in_sizes[0];
  int E = in_sizes[1];
  int B = out_size;           // output is [B,1] float32
  float* out = (float*)d_out;

  // Workspace carve-out (256B aligned)
  char* p = (char*)d_ws;
  auto alloc = [&](size_t bytes) -> char* {
    char* r = p;
    p += (bytes + 255) & ~(size_t)255;
    return r;
  };
  int nb = (N + 255) / 256;
  // coarse dst-buckets for CSR build write-locality
  int shift = 11;
  while ((((long)N + (1L << shift) - 1) >> shift) > 256) ++shift;
  int nbk = (int)(((long)N + (1L << shift) - 1) >> shift);

  int*   deg     = (int*)alloc((size_t)N * 4);
  int*   startv  = (int*)alloc((size_t)N * 4);
  int*   fillc   = (int*)alloc((size_t)N * 4);
  int*   bsum    = (int*)alloc((size_t)nb * 4);
  int*   gcur    = (int*)alloc((size_t)nbk * 4);
  int*   csr_src = (int*)alloc((size_t)E * 4);
  float* el      = (float*)alloc((size_t)N * 16);
  float* er      = (float*)alloc((size_t)N * 16);
  size_t fbytes  = (size_t)N * 128;
  size_t ebytes  = (size_t)E * 8;
  float* f       = (float*)alloc(fbytes > ebytes ? fbytes : ebytes);
  float* h       = (float*)alloc((size_t)N * 128);
  float* hg      = (float*)alloc((size_t)B * 32 * 4);
  uint2* ebuf    = (uint2*)f;   // disjoint lifetime: ebuf used only before fc_kernel writes f

  hipMemsetAsync(deg,   0, (size_t)N * 4, stream);
  hipMemsetAsync(fillc, 0, (size_t)N * 4, stream);

  int eb = (E + 255) / 256;
  count_deg_kernel<<<eb, 256, 0, stream>>>(dstp, E, deg);
  scan1_kernel<<<nb, 256, 0, stream>>>(deg, N, startv, bsum);
  scan2_kernel<<<1, 1024, 0, stream>>>(bsum, nb);
  scan3_kernel<<<nb, 256, 0, stream>>>(startv, N, bsum);
  init_gcur_kernel<<<(nbk + 255) / 256, 256, 0, stream>>>(startv, N, shift, nbk, gcur);
  bin_kernel<<<(E + 4095) / 4096, 256, 0, stream>>>(srcp, dstp, E, shift, nbk, gcur, ebuf);
  fill_csr2_kernel<<<eb, 256, 0, stream>>>(ebuf, E, startv, fillc, csr_src);

  int nblk = (N + 255) / 256;
  int ablk = (N + 3) / 4;
  // Layer 0: h_in = emb[node_ids]
  fc_kernel<<<nblk, 256, 0, stream>>>(emb, node_ids, W0, al0, ar0, N, f, el, er);
  gat_agg_kernel<<<ablk, 256, 0, stream>>>(csr_src, startv, deg, f, el, er, b0, N, h);
  // Layer 1: h_in = h
  fc_kernel<<<nblk, 256, 0, stream>>>(h, nullptr, W1, al1, ar1, N, f, el, er);
  gat_agg_kernel<<<ablk, 256, 0, stream>>>(csr_src, startv, deg, f, el, er, b1, N, h);

  pool_kernel<<<B, 256, 0, stream>>>(h, gid, N, hg);
  score_kernel<<<(B + 63) / 64, 64, 0, stream>>>(hg, sw1, sb1, sw2, sb2, B, out);
}

// Round 4
// 649.441 us; speedup vs baseline: 1.4944x; 1.2154x over previous
//
#include <hip/hip_runtime.h>
#include <math.h>

__device__ __forceinline__ float lrelu(float x){ return x > 0.f ? x : 0.2f * x; }

__global__ void count_deg_kernel(const int* __restrict__ dst, int E, int* __restrict__ deg){
  int e = blockIdx.x * blockDim.x + threadIdx.x;
  if (e < E) atomicAdd(&deg[dst[e]], 1);
}

__global__ void scan1_kernel(const int* __restrict__ deg, int n,
                             int* __restrict__ startv, int* __restrict__ bsum){
  __shared__ int sh[256];
  int t = threadIdx.x;
  int i = blockIdx.x * 256 + t;
  int v = (i < n) ? deg[i] : 0;
  sh[t] = v; __syncthreads();
  for (int off = 1; off < 256; off <<= 1){
    int x = (t >= off) ? sh[t - off] : 0;
    __syncthreads();
    sh[t] += x;
    __syncthreads();
  }
  if (i < n) startv[i] = sh[t] - v;          // exclusive local prefix
  if (t == 255) bsum[blockIdx.x] = sh[255];  // block total
}

__global__ void scan2_kernel(int* __restrict__ bsum, int nb){
  __shared__ int sh[1024];
  __shared__ int carry_s;
  int t = threadIdx.x;
  if (t == 0) carry_s = 0;
  __syncthreads();
  for (int base = 0; base < nb; base += 1024){
    int idx = base + t;
    int v = (idx < nb) ? bsum[idx] : 0;
    sh[t] = v; __syncthreads();
    for (int off = 1; off < 1024; off <<= 1){
      int x = (t >= off) ? sh[t - off] : 0;
      __syncthreads();
      sh[t] += x;
      __syncthreads();
    }
    int carry = carry_s;
    if (idx < nb) bsum[idx] = sh[t] - v + carry;  // exclusive across all
    __syncthreads();
    if (t == 0) carry_s = carry + sh[1023];
    __syncthreads();
  }
}

// final startv; also derives bucket starts (gcur) for the bin pass
__global__ void scan3_kernel(int* __restrict__ startv, int n, const int* __restrict__ bsum,
                             int shift, int* __restrict__ gcur){
  int i = blockIdx.x * 256 + threadIdx.x;
  if (i < n){
    int v = startv[i] + bsum[blockIdx.x];
    startv[i] = v;
    if ((i & ((1 << shift) - 1)) == 0) gcur[i >> shift] = v;
  }
}

// Bin edges by coarse dst-bucket so the CSR fill has write locality.
// 4096 edges per block; LDS histogram + LDS rank; one global atomic per (block,bucket).
__global__ __launch_bounds__(256) void bin_kernel(
    const int* __restrict__ src, const int* __restrict__ dst, int E, int shift, int nbk,
    int* __restrict__ gcur, uint2* __restrict__ ebuf)
{
  __shared__ int hist[256];
  __shared__ int lbase[256];
  int t = threadIdx.x;
  long base = (long)blockIdx.x * 4096;
  for (int i = t; i < nbk; i += 256) hist[i] = 0;
  __syncthreads();
  int s_[16], d_[16];
  #pragma unroll
  for (int k = 0; k < 16; ++k){
    long e = base + (long)k * 256 + t;
    if (e < E){
      s_[k] = src[e]; d_[k] = dst[e];
      atomicAdd(&hist[d_[k] >> shift], 1);
    } else d_[k] = -1;
  }
  __syncthreads();
  for (int i = t; i < nbk; i += 256){
    lbase[i] = atomicAdd(&gcur[i], hist[i]);
    hist[i] = 0;
  }
  __syncthreads();
  #pragma unroll
  for (int k = 0; k < 16; ++k){
    if (d_[k] >= 0){
      int b = d_[k] >> shift;
      int r = atomicAdd(&hist[b], 1);
      ebuf[lbase[b] + r] = make_uint2((unsigned)s_[k], (unsigned)d_[k]);
    }
  }
}

// Fill CSR from bucket-ordered edges: scattered writes stay in a small moving window.
__global__ void fill_csr2_kernel(const uint2* __restrict__ ebuf, int E,
                                 const int* __restrict__ startv, int* __restrict__ fillc,
                                 int* __restrict__ csr_src){
  int e = blockIdx.x * blockDim.x + threadIdx.x;
  if (e >= E) return;
  uint2 p = ebuf[e];
  int d = (int)p.y;
  int slot = startv[d] + atomicAdd(&fillc[d], 1);
  csr_src[slot] = (int)p.x;
}

// f = h @ W  (32x32), el/er = per-head dot with al/ar. One thread per node.
__global__ __launch_bounds__(256) void fc_kernel(
    const float* __restrict__ hin, const int* __restrict__ nid,
    const float* __restrict__ W, const float* __restrict__ al, const float* __restrict__ ar,
    int n, float* __restrict__ f, float* __restrict__ el, float* __restrict__ er)
{
  __shared__ __align__(16) float Ws[1024];
  __shared__ float als[32], ars[32];
  int t = threadIdx.x;
  for (int i = t; i < 1024; i += 256) Ws[i] = W[i];
  if (t < 32){ als[t] = al[t]; ars[t] = ar[t]; }
  __syncthreads();
  int i = blockIdx.x * 256 + t;
  if (i >= n) return;
  long row = nid ? (long)nid[i] : (long)i;
  const float4* hp = (const float4*)(hin + row * 32);
  float h[32];
  #pragma unroll
  for (int q = 0; q < 8; ++q){
    float4 v = hp[q];
    h[4*q+0] = v.x; h[4*q+1] = v.y; h[4*q+2] = v.z; h[4*q+3] = v.w;
  }
  float fv[32];
  #pragma unroll
  for (int j = 0; j < 32; j += 4){
    float ax = 0.f, ay = 0.f, az = 0.f, aw = 0.f;
    #pragma unroll
    for (int k = 0; k < 32; ++k){
      float hk = h[k];
      float4 w = *(const float4*)&Ws[k*32 + j];
      ax += hk * w.x; ay += hk * w.y; az += hk * w.z; aw += hk * w.w;
    }
    fv[j] = ax; fv[j+1] = ay; fv[j+2] = az; fv[j+3] = aw;
  }
  float4* fp = (float4*)(f + (size_t)i * 32);
  #pragma unroll
  for (int q = 0; q < 8; ++q)
    fp[q] = make_float4(fv[4*q], fv[4*q+1], fv[4*q+2], fv[4*q+3]);
  float elv[4], erv[4];
  #pragma unroll
  for (int hh = 0; hh < 4; ++hh){
    float a = 0.f, b = 0.f;
    #pragma unroll
    for (int d = 0; d < 8; ++d){
      a += fv[hh*8 + d] * als[hh*8 + d];
      b += fv[hh*8 + d] * ars[hh*8 + d];
    }
    elv[hh] = a; erv[hh] = b;
  }
  *(float4*)(el + (size_t)i * 4) = make_float4(elv[0], elv[1], elv[2], elv[3]);
  *(float4*)(er + (size_t)i * 4) = make_float4(erv[0], erv[1], erv[2], erv[3]);
}

// One wave per dst node. Fast path (deg<=64):
//  - per-lane edge: ex = exp(lrelu(el+er)) (no max shift: softmax is shift-invariant
//    and activations are O(0.1), no overflow risk), stored raw in LDS
//  - shuffle-sum s per head; NO per-edge normalization (divide once in epilogue)
//  - gather: 8 lanes per edge (float4 col-quad each), 8 edges in flight
__global__ __launch_bounds__(256) void gat_agg_kernel(
    const int* __restrict__ csr_src, const int* __restrict__ startv, const int* __restrict__ deg,
    const float* __restrict__ f, const float* __restrict__ el, const float* __restrict__ er,
    const float* __restrict__ bias, int n, float* __restrict__ hout)
{
  __shared__ int    su_s[4][64];
  __shared__ float4 ex_s[4][64];
  int wid  = threadIdx.x >> 6;
  int lane = threadIdx.x & 63;
  int v = blockIdx.x * 4 + wid;
  if (v >= n) return;
  int s = startv[v];
  int d = deg[v];
  float4 er4 = *(const float4*)(er + (size_t)v * 4);

  int cq    = lane & 7;    // col-quad: cols 4cq..4cq+3
  int g     = lane >> 3;   // edge group 0..7
  int headq = cq >> 1;     // head of this col-quad

  if (d > 64){
    // slow path: 3-pass global recompute (statistically never for Poisson(16))
    int col  = lane & 31;
    int half = lane >> 5;
    int head = col >> 3;
    float m0 = -1e30f, m1 = -1e30f, m2 = -1e30f, m3 = -1e30f;
    for (int i = lane; i < d; i += 64){
      int u = csr_src[s + i];
      float4 e4 = *(const float4*)(el + (size_t)u * 4);
      m0 = fmaxf(m0, lrelu(e4.x + er4.x));
      m1 = fmaxf(m1, lrelu(e4.y + er4.y));
      m2 = fmaxf(m2, lrelu(e4.z + er4.z));
      m3 = fmaxf(m3, lrelu(e4.w + er4.w));
    }
    #pragma unroll
    for (int off = 32; off >= 1; off >>= 1){
      m0 = fmaxf(m0, __shfl_xor(m0, off));
      m1 = fmaxf(m1, __shfl_xor(m1, off));
      m2 = fmaxf(m2, __shfl_xor(m2, off));
      m3 = fmaxf(m3, __shfl_xor(m3, off));
    }
    float s0 = 0.f, s1 = 0.f, s2 = 0.f, s3 = 0.f;
    for (int i = lane; i < d; i += 64){
      int u = csr_src[s + i];
      float4 e4 = *(const float4*)(el + (size_t)u * 4);
      s0 += expf(lrelu(e4.x + er4.x) - m0);
      s1 += expf(lrelu(e4.y + er4.y) - m1);
      s2 += expf(lrelu(e4.z + er4.z) - m2);
      s3 += expf(lrelu(e4.w + er4.w) - m3);
    }
    #pragma unroll
    for (int off = 32; off >= 1; off >>= 1){
      s0 += __shfl_xor(s0, off);
      s1 += __shfl_xor(s1, off);
      s2 += __shfl_xor(s2, off);
      s3 += __shfl_xor(s3, off);
    }
    float me  = head == 0 ? m0 : head == 1 ? m1 : head == 2 ? m2 : m3;
    float se  = head == 0 ? s0 : head == 1 ? s1 : head == 2 ? s2 : s3;
    float re  = 1.f / se;
    float ere = head == 0 ? er4.x : head == 1 ? er4.y : head == 2 ? er4.z : er4.w;
    float acc = 0.f;
    for (int i = half; i < d; i += 2){
      int u = csr_src[s + i];
      float e = lrelu(el[(size_t)u * 4 + head] + ere);
      float alpha = expf(e - me) * re;
      acc = fmaf(alpha, f[(size_t)u * 32 + col], acc);
    }
    acc += __shfl_xor(acc, 32);
    if (lane < 32){
      float o = acc + bias[col];
      hout[(size_t)v * 32 + col] = fmaxf(o, 0.f);
    }
    return;
  }

  float4 o4 = make_float4(0.f, 0.f, 0.f, 0.f);
  float s0 = 0.f, s1 = 0.f, s2 = 0.f, s3 = 0.f;
  if (d > 0){
    int*    suw = su_s[wid];
    float4* exw = ex_s[wid];
    float x0 = 0.f, x1 = 0.f, x2 = 0.f, x3 = 0.f;
    if (lane < d){
      int u = csr_src[s + lane];
      suw[lane] = u;
      float4 l4 = *(const float4*)(el + (size_t)u * 4);
      x0 = __expf(lrelu(l4.x + er4.x));
      x1 = __expf(lrelu(l4.y + er4.y));
      x2 = __expf(lrelu(l4.z + er4.z));
      x3 = __expf(lrelu(l4.w + er4.w));
      exw[lane] = make_float4(x0, x1, x2, x3);
    }
    s0 = x0; s1 = x1; s2 = x2; s3 = x3;
    #pragma unroll
    for (int off = 32; off >= 1; off >>= 1){
      s0 += __shfl_xor(s0, off);
      s1 += __shfl_xor(s1, off);
      s2 += __shfl_xor(s2, off);
      s3 += __shfl_xor(s3, off);
    }
    // DS ops of a wave complete in order; stop compiler reordering and drain
    // LDS before cross-lane reads. Wave-local data: no block barrier needed.
    asm volatile("s_waitcnt lgkmcnt(0)" ::: "memory");
    const float* exf = (const float*)exw;
    for (int i = g; i < d; i += 8){
      int u = suw[i];
      float a = exf[i * 4 + headq];
      const float4 f4 = *(const float4*)(f + (size_t)u * 32 + cq * 4);
      o4.x = fmaf(a, f4.x, o4.x);
      o4.y = fmaf(a, f4.y, o4.y);
      o4.z = fmaf(a, f4.z, o4.z);
      o4.w = fmaf(a, f4.w, o4.w);
    }
    #pragma unroll
    for (int off = 32; off >= 8; off >>= 1){
      o4.x += __shfl_xor(o4.x, off);
      o4.y += __shfl_xor(o4.y, off);
      o4.z += __shfl_xor(o4.z, off);
      o4.w += __shfl_xor(o4.w, off);
    }
  }
  if (lane < 8){
    float se = headq == 0 ? s0 : headq == 1 ? s1 : headq == 2 ? s2 : s3;
    float rs = (d > 0) ? 1.f / se : 0.f;
    float4 b4 = *(const float4*)(bias + cq * 4);
    float4 r;
    r.x = fmaxf(fmaf(o4.x, rs, b4.x), 0.f);
    r.y = fmaxf(fmaf(o4.y, rs, b4.y), 0.f);
    r.z = fmaxf(fmaf(o4.z, rs, b4.z), 0.f);
    r.w = fmaxf(fmaf(o4.w, rs, b4.w), 0.f);
    *(float4*)(hout + (size_t)v * 32 + cq * 4) = r;
  }
}

__device__ int lower_bound_dev(const int* a, int n, int key){
  int lo = 0, hi = n;
  while (lo < hi){
    int mid = (lo + hi) >> 1;
    if (a[mid] < key) lo = mid + 1; else hi = mid;
  }
  return lo;
}

__global__ void pool_kernel(const float* __restrict__ hout, const int* __restrict__ gid,
                            int n, float* __restrict__ hg){
  __shared__ int lohi[2];
  int g = blockIdx.x;
  int t = threadIdx.x;
  if (t < 2) lohi[t] = lower_bound_dev(gid, n, g + t);
  __syncthreads();
  int lo = lohi[0], hi = lohi[1];
  int cnt = hi - lo;
  int col = t & 31, r0 = t >> 5;
  float acc = 0.f;
  for (int r = r0; r < cnt; r += 8)
    acc += hout[(size_t)(lo + r) * 32 + col];
  __shared__ float red[256];
  red[t] = acc; __syncthreads();
  if (t < 128) red[t] += red[t + 128];
  __syncthreads();
  if (t < 64) red[t] += red[t + 64];
  __syncthreads();
  if (t < 32){
    float sum = red[t] + red[t + 32];
    hg[g * 32 + t] = sum / fmaxf((float)cnt, 1.f);
  }
}

__global__ void score_kernel(const float* __restrict__ hg, const float* __restrict__ sw1,
                             const float* __restrict__ sb1, const float* __restrict__ sw2,
                             const float* __restrict__ sb2, int B, float* __restrict__ out){
  int g = blockIdx.x * blockDim.x + threadIdx.x;
  if (g >= B) return;
  float hvec[32];
  const float4* hp = (const float4*)(hg + g * 32);
  #pragma unroll
  for (int q = 0; q < 8; ++q){
    float4 v = hp[q];
    hvec[4*q+0] = v.x; hvec[4*q+1] = v.y; hvec[4*q+2] = v.z; hvec[4*q+3] = v.w;
  }
  float o = sb2[0];
  #pragma unroll
  for (int j = 0; j < 32; ++j){
    float a = sb1[j];
    #pragma unroll
    for (int k = 0; k < 32; ++k) a += hvec[k] * sw1[k*32 + j];
    o += fmaxf(a, 0.f) * sw2[j];
  }
  out[g] = o;
}

extern "C" void kernel_launch(void* const* d_in, const int* in_sizes, int n_in,
                              void* d_out, int out_size, void* d_ws, size_t ws_size,
                              hipStream_t stream)
{
  const int*   node_ids = (const int*)d_in[0];
  const int*   srcp     = (const int*)d_in[1];
  const int*   dstp     = (const int*)d_in[2];
  const int*   gid      = (const int*)d_in[3];
  const float* emb      = (const float*)d_in[4];
  const float* W0       = (const float*)d_in[5];
  const float* al0      = (const float*)d_in[6];
  const float* ar0      = (const float*)d_in[7];
  const float* b0       = (const float*)d_in[8];
  const float* W1       = (const float*)d_in[9];
  const float* al1      = (const float*)d_in[10];
  const float* ar1      = (const float*)d_in[11];
  const float* b1       = (const float*)d_in[12];
  const float* sw1      = (const float*)d_in[13];
  const float* sb1      = (const float*)d_in[14];
  const float* sw2      = (const float*)d_in[15];
  const float* sb2      = (const float*)d_in[16];

  int N = in_sizes[0];
  int E = in_sizes[1];
  int B = out_size;           // output is [B,1] float32
  float* out = (float*)d_out;

  // Workspace carve-out (256B aligned)
  char* p = (char*)d_ws;
  auto alloc = [&](size_t bytes) -> char* {
    char* r = p;
    p += (bytes + 255) & ~(size_t)255;
    return r;
  };
  int nb = (N + 255) / 256;
  // coarse dst-buckets for CSR build write-locality
  int shift = 11;
  while ((((long)N + (1L << shift) - 1) >> shift) > 256) ++shift;
  int nbk = (int)(((long)N + (1L << shift) - 1) >> shift);

  int*   deg     = (int*)alloc((size_t)N * 4);
  int*   startv  = (int*)alloc((size_t)N * 4);
  int*   fillc   = (int*)alloc((size_t)N * 4);
  int*   bsum    = (int*)alloc((size_t)nb * 4);
  int*   gcur    = (int*)alloc((size_t)nbk * 4);
  int*   csr_src = (int*)alloc((size_t)E * 4);
  float* el      = (float*)alloc((size_t)N * 16);
  float* er      = (float*)alloc((size_t)N * 16);
  size_t fbytes  = (size_t)N * 128;
  size_t ebytes  = (size_t)E * 8;
  float* f       = (float*)alloc(fbytes > ebytes ? fbytes : ebytes);
  float* h       = (float*)alloc((size_t)N * 128);
  float* hg      = (float*)alloc((size_t)B * 32 * 4);
  uint2* ebuf    = (uint2*)f;   // disjoint lifetime: ebuf used only before fc_kernel writes f

  hipMemsetAsync(deg,   0, (size_t)N * 4, stream);
  hipMemsetAsync(fillc, 0, (size_t)N * 4, stream);

  int eb = (E + 255) / 256;
  count_deg_kernel<<<eb, 256, 0, stream>>>(dstp, E, deg);
  scan1_kernel<<<nb, 256, 0, stream>>>(deg, N, startv, bsum);
  scan2_kernel<<<1, 1024, 0, stream>>>(bsum, nb);
  scan3_kernel<<<nb, 256, 0, stream>>>(startv, N, bsum, shift, gcur);
  bin_kernel<<<(E + 4095) / 4096, 256, 0, stream>>>(srcp, dstp, E, shift, nbk, gcur, ebuf);
  fill_csr2_kernel<<<eb, 256, 0, stream>>>(ebuf, E, startv, fillc, csr_src);

  int nblk = (N + 255) / 256;
  int ablk = (N + 3) / 4;
  // Layer 0: h_in = emb[node_ids]
  fc_kernel<<<nblk, 256, 0, stream>>>(emb, node_ids, W0, al0, ar0, N, f, el, er);
  gat_agg_kernel<<<ablk, 256, 0, stream>>>(csr_src, startv, deg, f, el, er, b0, N, h);
  // Layer 1: h_in = h
  fc_kernel<<<nblk, 256, 0, stream>>>(h, nullptr, W1, al1, ar1, N, f, el, er);
  gat_agg_kernel<<<ablk, 256, 0, stream>>>(csr_src, startv, deg, f, el, er, b1, N, h);

  pool_kernel<<<B, 256, 0, stream>>>(h, gid, N, hg);
  score_kernel<<<(B + 63) / 64, 64, 0, stream>>>(hg, sw1, sb1, sw2, sb2, B, out);
}

// Round 5
// 557.714 us; speedup vs baseline: 1.7402x; 1.1645x over previous
//
#include <hip/hip_runtime.h>
#include <math.h>

__device__ __forceinline__ float lrelu(float x){ return x > 0.f ? x : 0.2f * x; }

__global__ void count_deg_kernel(const int* __restrict__ dst, int E, int* __restrict__ deg){
  int e = blockIdx.x * blockDim.x + threadIdx.x;
  if (e < E) atomicAdd(&deg[dst[e]], 1);
}

__global__ void scan1_kernel(const int* __restrict__ deg, int n,
                             int* __restrict__ startv, int* __restrict__ bsum){
  __shared__ int sh[256];
  int t = threadIdx.x;
  int i = blockIdx.x * 256 + t;
  int v = (i < n) ? deg[i] : 0;
  sh[t] = v; __syncthreads();
  for (int off = 1; off < 256; off <<= 1){
    int x = (t >= off) ? sh[t - off] : 0;
    __syncthreads();
    sh[t] += x;
    __syncthreads();
  }
  if (i < n) startv[i] = sh[t] - v;          // exclusive local prefix
  if (t == 255) bsum[blockIdx.x] = sh[255];  // block total
}

__global__ void scan2_kernel(int* __restrict__ bsum, int nb){
  __shared__ int sh[1024];
  __shared__ int carry_s;
  int t = threadIdx.x;
  if (t == 0) carry_s = 0;
  __syncthreads();
  for (int base = 0; base < nb; base += 1024){
    int idx = base + t;
    int v = (idx < nb) ? bsum[idx] : 0;
    sh[t] = v; __syncthreads();
    for (int off = 1; off < 1024; off <<= 1){
      int x = (t >= off) ? sh[t - off] : 0;
      __syncthreads();
      sh[t] += x;
      __syncthreads();
    }
    int carry = carry_s;
    if (idx < nb) bsum[idx] = sh[t] - v + carry;  // exclusive across all
    __syncthreads();
    if (t == 0) carry_s = carry + sh[1023];
    __syncthreads();
  }
}

// final startv; also derives bucket starts (gcur) for the bin pass
__global__ void scan3_kernel(int* __restrict__ startv, int n, const int* __restrict__ bsum,
                             int shift, int* __restrict__ gcur){
  int i = blockIdx.x * 256 + threadIdx.x;
  if (i < n){
    int v = startv[i] + bsum[blockIdx.x];
    startv[i] = v;
    if ((i & ((1 << shift) - 1)) == 0) gcur[i >> shift] = v;
  }
}

// Bin edges by coarse dst-bucket (packed u32: src<<shift | local_dst).
// 4096 edges per block; LDS histogram + rank; one global atomic per (block,bucket).
// After this kernel, gcur[b] == END offset of bucket b's edge range.
__global__ __launch_bounds__(256) void bin_kernel(
    const int* __restrict__ src, const int* __restrict__ dst, int E, int shift, int nbk,
    int* __restrict__ gcur, unsigned* __restrict__ ebuf)
{
  __shared__ int hist[512];
  __shared__ int lbase[512];
  int t = threadIdx.x;
  int mask = (1 << shift) - 1;
  long base = (long)blockIdx.x * 4096;
  for (int i = t; i < nbk; i += 256) hist[i] = 0;
  __syncthreads();
  int s_[16], d_[16];
  #pragma unroll
  for (int k = 0; k < 16; ++k){
    long e = base + (long)k * 256 + t;
    if (e < E){
      s_[k] = src[e]; d_[k] = dst[e];
      atomicAdd(&hist[d_[k] >> shift], 1);
    } else d_[k] = -1;
  }
  __syncthreads();
  for (int i = t; i < nbk; i += 256){
    lbase[i] = atomicAdd(&gcur[i], hist[i]);
    hist[i] = 0;
  }
  __syncthreads();
  #pragma unroll
  for (int k = 0; k < 16; ++k){
    if (d_[k] >= 0){
      int b = d_[k] >> shift;
      int r = atomicAdd(&hist[b], 1);
      ebuf[lbase[b] + r] = ((unsigned)s_[k] << shift) | (unsigned)(d_[k] & mask);
    }
  }
}

// One workgroup OWNS one bucket: per-node cursors in LDS, csr window written by
// a single CU/XCD so L2 lines fill completely (kills partial-line writeback).
__global__ __launch_bounds__(512) void fill_csr3_kernel(
    const unsigned* __restrict__ ebuf, const int* __restrict__ gcur_end,
    const int* __restrict__ startv, int E, int shift, int N,
    int* __restrict__ csr_src)
{
  __shared__ int cur[4096];              // supports shift <= 12
  int b = blockIdx.x;
  int t = threadIdx.x;
  int bsz = 1 << shift;
  int mask = bsz - 1;
  int nbase = b << shift;
  for (int i = t; i < bsz; i += 512){
    int node = nbase + i;
    cur[i] = (node < N) ? startv[node] : 0;
  }
  __syncthreads();
  int gs = (b == 0) ? 0 : gcur_end[b - 1];
  int ge = gcur_end[b];
  for (int e = gs + t; e < ge; e += 512){
    unsigned v = ebuf[e];
    int slot = atomicAdd(&cur[v & mask], 1);
    csr_src[slot] = (int)(v >> shift);
  }
}

// f = h @ W  (32x32), el/er = per-head dot with al/ar. One thread per node.
__global__ __launch_bounds__(256) void fc_kernel(
    const float* __restrict__ hin, const int* __restrict__ nid,
    const float* __restrict__ W, const float* __restrict__ al, const float* __restrict__ ar,
    int n, float* __restrict__ f, float* __restrict__ el, float* __restrict__ er)
{
  __shared__ __align__(16) float Ws[1024];
  __shared__ float als[32], ars[32];
  int t = threadIdx.x;
  for (int i = t; i < 1024; i += 256) Ws[i] = W[i];
  if (t < 32){ als[t] = al[t]; ars[t] = ar[t]; }
  __syncthreads();
  int i = blockIdx.x * 256 + t;
  if (i >= n) return;
  long row = nid ? (long)nid[i] : (long)i;
  const float4* hp = (const float4*)(hin + row * 32);
  float h[32];
  #pragma unroll
  for (int q = 0; q < 8; ++q){
    float4 v = hp[q];
    h[4*q+0] = v.x; h[4*q+1] = v.y; h[4*q+2] = v.z; h[4*q+3] = v.w;
  }
  float fv[32];
  #pragma unroll
  for (int j = 0; j < 32; j += 4){
    float ax = 0.f, ay = 0.f, az = 0.f, aw = 0.f;
    #pragma unroll
    for (int k = 0; k < 32; ++k){
      float hk = h[k];
      float4 w = *(const float4*)&Ws[k*32 + j];
      ax += hk * w.x; ay += hk * w.y; az += hk * w.z; aw += hk * w.w;
    }
    fv[j] = ax; fv[j+1] = ay; fv[j+2] = az; fv[j+3] = aw;
  }
  float4* fp = (float4*)(f + (size_t)i * 32);
  #pragma unroll
  for (int q = 0; q < 8; ++q)
    fp[q] = make_float4(fv[4*q], fv[4*q+1], fv[4*q+2], fv[4*q+3]);
  float elv[4], erv[4];
  #pragma unroll
  for (int hh = 0; hh < 4; ++hh){
    float a = 0.f, b = 0.f;
    #pragma unroll
    for (int d = 0; d < 8; ++d){
      a += fv[hh*8 + d] * als[hh*8 + d];
      b += fv[hh*8 + d] * ars[hh*8 + d];
    }
    elv[hh] = a; erv[hh] = b;
  }
  *(float4*)(el + (size_t)i * 4) = make_float4(elv[0], elv[1], elv[2], elv[3]);
  *(float4*)(er + (size_t)i * 4) = make_float4(erv[0], erv[1], erv[2], erv[3]);
}

// One wave per dst node. Fast path (deg<=64):
//  - per-lane edge: ex = exp(lrelu(el+er)) (softmax shift-invariant; activations
//    O(0.1), no overflow), raw in LDS; normalize once in epilogue
//  - gather: 8 lanes per edge (float4 col-quad each), 8 edges in flight
__global__ __launch_bounds__(256) void gat_agg_kernel(
    const int* __restrict__ csr_src, const int* __restrict__ startv, const int* __restrict__ deg,
    const float* __restrict__ f, const float* __restrict__ el, const float* __restrict__ er,
    const float* __restrict__ bias, int n, float* __restrict__ hout)
{
  __shared__ int    su_s[4][64];
  __shared__ float4 ex_s[4][64];
  int wid  = threadIdx.x >> 6;
  int lane = threadIdx.x & 63;
  int v = blockIdx.x * 4 + wid;
  if (v >= n) return;
  int s = startv[v];
  int d = deg[v];
  float4 er4 = *(const float4*)(er + (size_t)v * 4);

  int cq    = lane & 7;    // col-quad: cols 4cq..4cq+3
  int g     = lane >> 3;   // edge group 0..7
  int headq = cq >> 1;     // head of this col-quad

  if (d > 64){
    // slow path: 3-pass global recompute (statistically never for Poisson(16))
    int col  = lane & 31;
    int half = lane >> 5;
    int head = col >> 3;
    float m0 = -1e30f, m1 = -1e30f, m2 = -1e30f, m3 = -1e30f;
    for (int i = lane; i < d; i += 64){
      int u = csr_src[s + i];
      float4 e4 = *(const float4*)(el + (size_t)u * 4);
      m0 = fmaxf(m0, lrelu(e4.x + er4.x));
      m1 = fmaxf(m1, lrelu(e4.y + er4.y));
      m2 = fmaxf(m2, lrelu(e4.z + er4.z));
      m3 = fmaxf(m3, lrelu(e4.w + er4.w));
    }
    #pragma unroll
    for (int off = 32; off >= 1; off >>= 1){
      m0 = fmaxf(m0, __shfl_xor(m0, off));
      m1 = fmaxf(m1, __shfl_xor(m1, off));
      m2 = fmaxf(m2, __shfl_xor(m2, off));
      m3 = fmaxf(m3, __shfl_xor(m3, off));
    }
    float s0 = 0.f, s1 = 0.f, s2 = 0.f, s3 = 0.f;
    for (int i = lane; i < d; i += 64){
      int u = csr_src[s + i];
      float4 e4 = *(const float4*)(el + (size_t)u * 4);
      s0 += expf(lrelu(e4.x + er4.x) - m0);
      s1 += expf(lrelu(e4.y + er4.y) - m1);
      s2 += expf(lrelu(e4.z + er4.z) - m2);
      s3 += expf(lrelu(e4.w + er4.w) - m3);
    }
    #pragma unroll
    for (int off = 32; off >= 1; off >>= 1){
      s0 += __shfl_xor(s0, off);
      s1 += __shfl_xor(s1, off);
      s2 += __shfl_xor(s2, off);
      s3 += __shfl_xor(s3, off);
    }
    float me  = head == 0 ? m0 : head == 1 ? m1 : head == 2 ? m2 : m3;
    float se  = head == 0 ? s0 : head == 1 ? s1 : head == 2 ? s2 : s3;
    float re  = 1.f / se;
    float ere = head == 0 ? er4.x : head == 1 ? er4.y : head == 2 ? er4.z : er4.w;
    float acc = 0.f;
    for (int i = half; i < d; i += 2){
      int u = csr_src[s + i];
      float e = lrelu(el[(size_t)u * 4 + head] + ere);
      float alpha = expf(e - me) * re;
      acc = fmaf(alpha, f[(size_t)u * 32 + col], acc);
    }
    acc += __shfl_xor(acc, 32);
    if (lane < 32){
      float o = acc + bias[col];
      hout[(size_t)v * 32 + col] = fmaxf(o, 0.f);
    }
    return;
  }

  float4 o4 = make_float4(0.f, 0.f, 0.f, 0.f);
  float s0 = 0.f, s1 = 0.f, s2 = 0.f, s3 = 0.f;
  if (d > 0){
    int*    suw = su_s[wid];
    float4* exw = ex_s[wid];
    float x0 = 0.f, x1 = 0.f, x2 = 0.f, x3 = 0.f;
    if (lane < d){
      int u = csr_src[s + lane];
      suw[lane] = u;
      float4 l4 = *(const float4*)(el + (size_t)u * 4);
      x0 = __expf(lrelu(l4.x + er4.x));
      x1 = __expf(lrelu(l4.y + er4.y));
      x2 = __expf(lrelu(l4.z + er4.z));
      x3 = __expf(lrelu(l4.w + er4.w));
      exw[lane] = make_float4(x0, x1, x2, x3);
    }
    s0 = x0; s1 = x1; s2 = x2; s3 = x3;
    #pragma unroll
    for (int off = 32; off >= 1; off >>= 1){
      s0 += __shfl_xor(s0, off);
      s1 += __shfl_xor(s1, off);
      s2 += __shfl_xor(s2, off);
      s3 += __shfl_xor(s3, off);
    }
    // DS ops of a wave complete in order; stop compiler reordering and drain
    // LDS before cross-lane reads. Wave-local data: no block barrier needed.
    asm volatile("s_waitcnt lgkmcnt(0)" ::: "memory");
    const float* exf = (const float*)exw;
    for (int i = g; i < d; i += 8){
      int u = suw[i];
      float a = exf[i * 4 + headq];
      const float4 f4 = *(const float4*)(f + (size_t)u * 32 + cq * 4);
      o4.x = fmaf(a, f4.x, o4.x);
      o4.y = fmaf(a, f4.y, o4.y);
      o4.z = fmaf(a, f4.z, o4.z);
      o4.w = fmaf(a, f4.w, o4.w);
    }
    #pragma unroll
    for (int off = 32; off >= 8; off >>= 1){
      o4.x += __shfl_xor(o4.x, off);
      o4.y += __shfl_xor(o4.y, off);
      o4.z += __shfl_xor(o4.z, off);
      o4.w += __shfl_xor(o4.w, off);
    }
  }
  if (lane < 8){
    float se = headq == 0 ? s0 : headq == 1 ? s1 : headq == 2 ? s2 : s3;
    float rs = (d > 0) ? 1.f / se : 0.f;
    float4 b4 = *(const float4*)(bias + cq * 4);
    float4 r;
    r.x = fmaxf(fmaf(o4.x, rs, b4.x), 0.f);
    r.y = fmaxf(fmaf(o4.y, rs, b4.y), 0.f);
    r.z = fmaxf(fmaf(o4.z, rs, b4.z), 0.f);
    r.w = fmaxf(fmaf(o4.w, rs, b4.w), 0.f);
    *(float4*)(hout + (size_t)v * 32 + cq * 4) = r;
  }
}

__device__ int lower_bound_dev(const int* a, int n, int key){
  int lo = 0, hi = n;
  while (lo < hi){
    int mid = (lo + hi) >> 1;
    if (a[mid] < key) lo = mid + 1; else hi = mid;
  }
  return lo;
}

__global__ void pool_kernel(const float* __restrict__ hout, const int* __restrict__ gid,
                            int n, float* __restrict__ hg){
  __shared__ int lohi[2];
  int g = blockIdx.x;
  int t = threadIdx.x;
  if (t < 2) lohi[t] = lower_bound_dev(gid, n, g + t);
  __syncthreads();
  int lo = lohi[0], hi = lohi[1];
  int cnt = hi - lo;
  int col = t & 31, r0 = t >> 5;
  float acc = 0.f;
  for (int r = r0; r < cnt; r += 8)
    acc += hout[(size_t)(lo + r) * 32 + col];
  __shared__ float red[256];
  red[t] = acc; __syncthreads();
  if (t < 128) red[t] += red[t + 128];
  __syncthreads();
  if (t < 64) red[t] += red[t + 64];
  __syncthreads();
  if (t < 32){
    float sum = red[t] + red[t + 32];
    hg[g * 32 + t] = sum / fmaxf((float)cnt, 1.f);
  }
}

__global__ void score_kernel(const float* __restrict__ hg, const float* __restrict__ sw1,
                             const float* __restrict__ sb1, const float* __restrict__ sw2,
                             const float* __restrict__ sb2, int B, float* __restrict__ out){
  int g = blockIdx.x * blockDim.x + threadIdx.x;
  if (g >= B) return;
  float hvec[32];
  const float4* hp = (const float4*)(hg + g * 32);
  #pragma unroll
  for (int q = 0; q < 8; ++q){
    float4 v = hp[q];
    hvec[4*q+0] = v.x; hvec[4*q+1] = v.y; hvec[4*q+2] = v.z; hvec[4*q+3] = v.w;
  }
  float o = sb2[0];
  #pragma unroll
  for (int j = 0; j < 32; ++j){
    float a = sb1[j];
    #pragma unroll
    for (int k = 0; k < 32; ++k) a += hvec[k] * sw1[k*32 + j];
    o += fmaxf(a, 0.f) * sw2[j];
  }
  out[g] = o;
}

extern "C" void kernel_launch(void* const* d_in, const int* in_sizes, int n_in,
                              void* d_out, int out_size, void* d_ws, size_t ws_size,
                              hipStream_t stream)
{
  const int*   node_ids = (const int*)d_in[0];
  const int*   srcp     = (const int*)d_in[1];
  const int*   dstp     = (const int*)d_in[2];
  const int*   gid      = (const int*)d_in[3];
  const float* emb      = (const float*)d_in[4];
  const float* W0       = (const float*)d_in[5];
  const float* al0      = (const float*)d_in[6];
  const float* ar0      = (const float*)d_in[7];
  const float* b0       = (const float*)d_in[8];
  const float* W1       = (const float*)d_in[9];
  const float* al1      = (const float*)d_in[10];
  const float* ar1      = (const float*)d_in[11];
  const float* b1       = (const float*)d_in[12];
  const float* sw1      = (const float*)d_in[13];
  const float* sb1      = (const float*)d_in[14];
  const float* sw2      = (const float*)d_in[15];
  const float* sb2      = (const float*)d_in[16];

  int N = in_sizes[0];
  int E = in_sizes[1];
  int B = out_size;           // output is [B,1] float32
  float* out = (float*)d_out;

  // Workspace carve-out (256B aligned)
  char* p = (char*)d_ws;
  auto alloc = [&](size_t bytes) -> char* {
    char* r = p;
    p += (bytes + 255) & ~(size_t)255;
    return r;
  };
  int nb = (N + 255) / 256;
  // Coarse dst-buckets: one workgroup per bucket in the fill pass.
  // Constraints: nbk <= 512 (bin LDS hist), bsz <= 4096 (fill LDS cursors),
  // src must fit in (32-shift) bits for the packed edge record.
  int shift = 9;
  while ((((long)N + (1L << shift) - 1) >> shift) > 512 && shift < 12) ++shift;
  int nbk = (int)(((long)N + (1L << shift) - 1) >> shift);

  int*      deg     = (int*)alloc((size_t)N * 4);
  int*      startv  = (int*)alloc((size_t)N * 4);
  int*      bsum    = (int*)alloc((size_t)nb * 4);
  int*      gcur    = (int*)alloc((size_t)nbk * 4);
  int*      csr_src = (int*)alloc((size_t)E * 4);
  float*    el      = (float*)alloc((size_t)N * 16);
  float*    er      = (float*)alloc((size_t)N * 16);
  size_t fbytes  = (size_t)N * 128;
  size_t ebytes  = (size_t)E * 4;
  float*    f       = (float*)alloc(fbytes > ebytes ? fbytes : ebytes);
  float*    h       = (float*)alloc((size_t)N * 128);
  float*    hg      = (float*)alloc((size_t)B * 32 * 4);
  unsigned* ebuf    = (unsigned*)f;  // disjoint lifetime: consumed before fc writes f

  hipMemsetAsync(deg, 0, (size_t)N * 4, stream);

  int eb = (E + 255) / 256;
  count_deg_kernel<<<eb, 256, 0, stream>>>(dstp, E, deg);
  scan1_kernel<<<nb, 256, 0, stream>>>(deg, N, startv, bsum);
  scan2_kernel<<<1, 1024, 0, stream>>>(bsum, nb);
  scan3_kernel<<<nb, 256, 0, stream>>>(startv, N, bsum, shift, gcur);
  bin_kernel<<<(E + 4095) / 4096, 256, 0, stream>>>(srcp, dstp, E, shift, nbk, gcur, ebuf);
  // after bin: gcur[b] == end offset of bucket b
  fill_csr3_kernel<<<nbk, 512, 0, stream>>>(ebuf, gcur, startv, E, shift, N, csr_src);

  int nblk = (N + 255) / 256;
  int ablk = (N + 3) / 4;
  // Layer 0: h_in = emb[node_ids]
  fc_kernel<<<nblk, 256, 0, stream>>>(emb, node_ids, W0, al0, ar0, N, f, el, er);
  gat_agg_kernel<<<ablk, 256, 0, stream>>>(csr_src, startv, deg, f, el, er, b0, N, h);
  // Layer 1: h_in = h
  fc_kernel<<<nblk, 256, 0, stream>>>(h, nullptr, W1, al1, ar1, N, f, el, er);
  gat_agg_kernel<<<ablk, 256, 0, stream>>>(csr_src, startv, deg, f, el, er, b1, N, h);

  pool_kernel<<<B, 256, 0, stream>>>(h, gid, N, hg);
  score_kernel<<<(B + 63) / 64, 64, 0, stream>>>(hg, sw1, sb1, sw2, sb2, B, out);
}

// Round 6
// 453.264 us; speedup vs baseline: 2.1412x; 1.2304x over previous
//
#include <hip/hip_runtime.h>
#include <math.h>

__device__ __forceinline__ float lrelu(float x){ return x > 0.f ? x : 0.2f * x; }

// Per-block LDS histogram of dst-buckets -> few global atomics per block.
__global__ __launch_bounds__(256) void bhist_kernel(
    const int* __restrict__ dst, int E, int shift, int nbk, int* __restrict__ bcount)
{
  __shared__ int hist[512];
  int t = threadIdx.x;
  for (int i = t; i < nbk; i += 256) hist[i] = 0;
  __syncthreads();
  long base = (long)blockIdx.x * 4096;
  #pragma unroll
  for (int k = 0; k < 16; ++k){
    long e = base + (long)k * 256 + t;
    if (e < E) atomicAdd(&hist[dst[e] >> shift], 1);
  }
  __syncthreads();
  for (int i = t; i < nbk; i += 256){
    int v = hist[i];
    if (v) atomicAdd(&bcount[i], v);
  }
}

// Single-block exclusive scan of bucket counts -> bucket start cursors.
__global__ __launch_bounds__(512) void bscan_kernel(
    const int* __restrict__ bcount, int nbk, int* __restrict__ gcur)
{
  __shared__ int sh[512];
  int t = threadIdx.x;
  int v = (t < nbk) ? bcount[t] : 0;
  sh[t] = v; __syncthreads();
  for (int off = 1; off < 512; off <<= 1){
    int x = (t >= off) ? sh[t - off] : 0;
    __syncthreads();
    sh[t] += x;
    __syncthreads();
  }
  if (t < nbk) gcur[t] = sh[t] - v;   // exclusive bucket start
}

// Bin edges by coarse dst-bucket (packed u32: src<<shift | local_dst).
// 4096 edges per block; LDS histogram + rank; one global atomic per (block,bucket).
// After this kernel, gcur[b] == END offset of bucket b's edge range.
__global__ __launch_bounds__(256) void bin_kernel(
    const int* __restrict__ src, const int* __restrict__ dst, int E, int shift, int nbk,
    int* __restrict__ gcur, unsigned* __restrict__ ebuf)
{
  __shared__ int hist[512];
  __shared__ int lbase[512];
  int t = threadIdx.x;
  int mask = (1 << shift) - 1;
  long base = (long)blockIdx.x * 4096;
  for (int i = t; i < nbk; i += 256) hist[i] = 0;
  __syncthreads();
  int s_[16], d_[16];
  #pragma unroll
  for (int k = 0; k < 16; ++k){
    long e = base + (long)k * 256 + t;
    if (e < E){
      s_[k] = src[e]; d_[k] = dst[e];
      atomicAdd(&hist[d_[k] >> shift], 1);
    } else d_[k] = -1;
  }
  __syncthreads();
  for (int i = t; i < nbk; i += 256){
    lbase[i] = atomicAdd(&gcur[i], hist[i]);
    hist[i] = 0;
  }
  __syncthreads();
  #pragma unroll
  for (int k = 0; k < 16; ++k){
    if (d_[k] >= 0){
      int b = d_[k] >> shift;
      int r = atomicAdd(&hist[b], 1);
      ebuf[lbase[b] + r] = ((unsigned)s_[k] << shift) | (unsigned)(d_[k] & mask);
    }
  }
}

// One workgroup OWNS one bucket: LDS per-node degree histogram -> block-local
// exclusive scan -> coalesced atomic-free startv/deg writes -> LDS-cursor CSR
// placement. Bucket's csr window written by a single CU (full-line writeback);
// bucket's ebuf slice (~32KB) stays L2-resident across its two reads.
__global__ __launch_bounds__(512) void fill_csr4_kernel(
    const unsigned* __restrict__ ebuf, const int* __restrict__ bend,
    int shift, int N, int* __restrict__ startv, int* __restrict__ deg,
    int* __restrict__ csr_src)
{
  __shared__ int cnt[4096];               // supports shift <= 12
  __shared__ int psum[512];
  int b = blockIdx.x;
  int t = threadIdx.x;
  int bsz = 1 << shift;
  int mask = bsz - 1;
  int nbase = b << shift;
  for (int i = t; i < bsz; i += 512) cnt[i] = 0;
  __syncthreads();
  int gs = (b == 0) ? 0 : bend[b - 1];
  int ge = bend[b];
  for (int e = gs + t; e < ge; e += 512)
    atomicAdd(&cnt[ebuf[e] & mask], 1);
  __syncthreads();
  // two-level exclusive scan over cnt[0..bsz)
  int k = bsz >> 9;                       // elems per thread (>=1)
  int base = t * k;
  int loc = 0;
  for (int j = 0; j < k; ++j) loc += cnt[base + j];
  psum[t] = loc;
  __syncthreads();
  for (int off = 1; off < 512; off <<= 1){
    int x = (t >= off) ? psum[t - off] : 0;
    __syncthreads();
    psum[t] += x;
    __syncthreads();
  }
  int run = gs + psum[t] - loc;           // global exclusive prefix for chunk
  for (int j = 0; j < k; ++j){
    int node = nbase + base + j;
    int c = cnt[base + j];
    cnt[base + j] = run;                  // becomes placement cursor
    if (node < N){ startv[node] = run; deg[node] = c; }
    run += c;
  }
  __syncthreads();
  for (int e = gs + t; e < ge; e += 512){
    unsigned v = ebuf[e];
    int slot = atomicAdd(&cnt[v & mask], 1);
    csr_src[slot] = (int)(v >> shift);
  }
}

// f = h @ W  (32x32), el/er = per-head dot with al/ar. One thread per node.
__global__ __launch_bounds__(256) void fc_kernel(
    const float* __restrict__ hin, const int* __restrict__ nid,
    const float* __restrict__ W, const float* __restrict__ al, const float* __restrict__ ar,
    int n, float* __restrict__ f, float* __restrict__ el, float* __restrict__ er)
{
  __shared__ __align__(16) float Ws[1024];
  __shared__ float als[32], ars[32];
  int t = threadIdx.x;
  for (int i = t; i < 1024; i += 256) Ws[i] = W[i];
  if (t < 32){ als[t] = al[t]; ars[t] = ar[t]; }
  __syncthreads();
  int i = blockIdx.x * 256 + t;
  if (i >= n) return;
  long row = nid ? (long)nid[i] : (long)i;
  const float4* hp = (const float4*)(hin + row * 32);
  float h[32];
  #pragma unroll
  for (int q = 0; q < 8; ++q){
    float4 v = hp[q];
    h[4*q+0] = v.x; h[4*q+1] = v.y; h[4*q+2] = v.z; h[4*q+3] = v.w;
  }
  float fv[32];
  #pragma unroll
  for (int j = 0; j < 32; j += 4){
    float ax = 0.f, ay = 0.f, az = 0.f, aw = 0.f;
    #pragma unroll
    for (int k = 0; k < 32; ++k){
      float hk = h[k];
      float4 w = *(const float4*)&Ws[k*32 + j];
      ax += hk * w.x; ay += hk * w.y; az += hk * w.z; aw += hk * w.w;
    }
    fv[j] = ax; fv[j+1] = ay; fv[j+2] = az; fv[j+3] = aw;
  }
  float4* fp = (float4*)(f + (size_t)i * 32);
  #pragma unroll
  for (int q = 0; q < 8; ++q)
    fp[q] = make_float4(fv[4*q], fv[4*q+1], fv[4*q+2], fv[4*q+3]);
  float elv[4], erv[4];
  #pragma unroll
  for (int hh = 0; hh < 4; ++hh){
    float a = 0.f, b = 0.f;
    #pragma unroll
    for (int d = 0; d < 8; ++d){
      a += fv[hh*8 + d] * als[hh*8 + d];
      b += fv[hh*8 + d] * ars[hh*8 + d];
    }
    elv[hh] = a; erv[hh] = b;
  }
  *(float4*)(el + (size_t)i * 4) = make_float4(elv[0], elv[1], elv[2], elv[3]);
  *(float4*)(er + (size_t)i * 4) = make_float4(erv[0], erv[1], erv[2], erv[3]);
}

// One wave per dst node. Fast path (deg<=64):
//  - per-lane edge: ex = exp(lrelu(el+er)) (softmax shift-invariant; activations
//    O(0.1), no overflow), raw in LDS; normalize once in epilogue
//  - gather: 8 lanes per edge (float4 col-quad each), 8 edges in flight
__global__ __launch_bounds__(256) void gat_agg_kernel(
    const int* __restrict__ csr_src, const int* __restrict__ startv, const int* __restrict__ deg,
    const float* __restrict__ f, const float* __restrict__ el, const float* __restrict__ er,
    const float* __restrict__ bias, int n, float* __restrict__ hout)
{
  __shared__ int    su_s[4][64];
  __shared__ float4 ex_s[4][64];
  int wid  = threadIdx.x >> 6;
  int lane = threadIdx.x & 63;
  int v = blockIdx.x * 4 + wid;
  if (v >= n) return;
  int s = startv[v];
  int d = deg[v];
  float4 er4 = *(const float4*)(er + (size_t)v * 4);

  int cq    = lane & 7;    // col-quad: cols 4cq..4cq+3
  int g     = lane >> 3;   // edge group 0..7
  int headq = cq >> 1;     // head of this col-quad

  if (d > 64){
    // slow path: 3-pass global recompute (statistically never for Poisson(16))
    int col  = lane & 31;
    int half = lane >> 5;
    int head = col >> 3;
    float m0 = -1e30f, m1 = -1e30f, m2 = -1e30f, m3 = -1e30f;
    for (int i = lane; i < d; i += 64){
      int u = csr_src[s + i];
      float4 e4 = *(const float4*)(el + (size_t)u * 4);
      m0 = fmaxf(m0, lrelu(e4.x + er4.x));
      m1 = fmaxf(m1, lrelu(e4.y + er4.y));
      m2 = fmaxf(m2, lrelu(e4.z + er4.z));
      m3 = fmaxf(m3, lrelu(e4.w + er4.w));
    }
    #pragma unroll
    for (int off = 32; off >= 1; off >>= 1){
      m0 = fmaxf(m0, __shfl_xor(m0, off));
      m1 = fmaxf(m1, __shfl_xor(m1, off));
      m2 = fmaxf(m2, __shfl_xor(m2, off));
      m3 = fmaxf(m3, __shfl_xor(m3, off));
    }
    float s0 = 0.f, s1 = 0.f, s2 = 0.f, s3 = 0.f;
    for (int i = lane; i < d; i += 64){
      int u = csr_src[s + i];
      float4 e4 = *(const float4*)(el + (size_t)u * 4);
      s0 += expf(lrelu(e4.x + er4.x) - m0);
      s1 += expf(lrelu(e4.y + er4.y) - m1);
      s2 += expf(lrelu(e4.z + er4.z) - m2);
      s3 += expf(lrelu(e4.w + er4.w) - m3);
    }
    #pragma unroll
    for (int off = 32; off >= 1; off >>= 1){
      s0 += __shfl_xor(s0, off);
      s1 += __shfl_xor(s1, off);
      s2 += __shfl_xor(s2, off);
      s3 += __shfl_xor(s3, off);
    }
    float me  = head == 0 ? m0 : head == 1 ? m1 : head == 2 ? m2 : m3;
    float se  = head == 0 ? s0 : head == 1 ? s1 : head == 2 ? s2 : s3;
    float re  = 1.f / se;
    float ere = head == 0 ? er4.x : head == 1 ? er4.y : head == 2 ? er4.z : er4.w;
    float acc = 0.f;
    for (int i = half; i < d; i += 2){
      int u = csr_src[s + i];
      float e = lrelu(el[(size_t)u * 4 + head] + ere);
      float alpha = expf(e - me) * re;
      acc = fmaf(alpha, f[(size_t)u * 32 + col], acc);
    }
    acc += __shfl_xor(acc, 32);
    if (lane < 32){
      float o = acc + bias[col];
      hout[(size_t)v * 32 + col] = fmaxf(o, 0.f);
    }
    return;
  }

  float4 o4 = make_float4(0.f, 0.f, 0.f, 0.f);
  float s0 = 0.f, s1 = 0.f, s2 = 0.f, s3 = 0.f;
  if (d > 0){
    int*    suw = su_s[wid];
    float4* exw = ex_s[wid];
    float x0 = 0.f, x1 = 0.f, x2 = 0.f, x3 = 0.f;
    if (lane < d){
      int u = csr_src[s + lane];
      suw[lane] = u;
      float4 l4 = *(const float4*)(el + (size_t)u * 4);
      x0 = __expf(lrelu(l4.x + er4.x));
      x1 = __expf(lrelu(l4.y + er4.y));
      x2 = __expf(lrelu(l4.z + er4.z));
      x3 = __expf(lrelu(l4.w + er4.w));
      exw[lane] = make_float4(x0, x1, x2, x3);
    }
    s0 = x0; s1 = x1; s2 = x2; s3 = x3;
    #pragma unroll
    for (int off = 32; off >= 1; off >>= 1){
      s0 += __shfl_xor(s0, off);
      s1 += __shfl_xor(s1, off);
      s2 += __shfl_xor(s2, off);
      s3 += __shfl_xor(s3, off);
    }
    // DS ops of a wave complete in order; stop compiler reordering and drain
    // LDS before cross-lane reads. Wave-local data: no block barrier needed.
    asm volatile("s_waitcnt lgkmcnt(0)" ::: "memory");
    const float* exf = (const float*)exw;
    for (int i = g; i < d; i += 8){
      int u = suw[i];
      float a = exf[i * 4 + headq];
      const float4 f4 = *(const float4*)(f + (size_t)u * 32 + cq * 4);
      o4.x = fmaf(a, f4.x, o4.x);
      o4.y = fmaf(a, f4.y, o4.y);
      o4.z = fmaf(a, f4.z, o4.z);
      o4.w = fmaf(a, f4.w, o4.w);
    }
    #pragma unroll
    for (int off = 32; off >= 8; off >>= 1){
      o4.x += __shfl_xor(o4.x, off);
      o4.y += __shfl_xor(o4.y, off);
      o4.z += __shfl_xor(o4.z, off);
      o4.w += __shfl_xor(o4.w, off);
    }
  }
  if (lane < 8){
    float se = headq == 0 ? s0 : headq == 1 ? s1 : headq == 2 ? s2 : s3;
    float rs = (d > 0) ? 1.f / se : 0.f;
    float4 b4 = *(const float4*)(bias + cq * 4);
    float4 r;
    r.x = fmaxf(fmaf(o4.x, rs, b4.x), 0.f);
    r.y = fmaxf(fmaf(o4.y, rs, b4.y), 0.f);
    r.z = fmaxf(fmaf(o4.z, rs, b4.z), 0.f);
    r.w = fmaxf(fmaf(o4.w, rs, b4.w), 0.f);
    *(float4*)(hout + (size_t)v * 32 + cq * 4) = r;
  }
}

__device__ int lower_bound_dev(const int* a, int n, int key){
  int lo = 0, hi = n;
  while (lo < hi){
    int mid = (lo + hi) >> 1;
    if (a[mid] < key) lo = mid + 1; else hi = mid;
  }
  return lo;
}

__global__ void pool_kernel(const float* __restrict__ hout, const int* __restrict__ gid,
                            int n, float* __restrict__ hg){
  __shared__ int lohi[2];
  int g = blockIdx.x;
  int t = threadIdx.x;
  if (t < 2) lohi[t] = lower_bound_dev(gid, n, g + t);
  __syncthreads();
  int lo = lohi[0], hi = lohi[1];
  int cnt = hi - lo;
  int col = t & 31, r0 = t >> 5;
  float acc = 0.f;
  for (int r = r0; r < cnt; r += 8)
    acc += hout[(size_t)(lo + r) * 32 + col];
  __shared__ float red[256];
  red[t] = acc; __syncthreads();
  if (t < 128) red[t] += red[t + 128];
  __syncthreads();
  if (t < 64) red[t] += red[t + 64];
  __syncthreads();
  if (t < 32){
    float sum = red[t] + red[t + 32];
    hg[g * 32 + t] = sum / fmaxf((float)cnt, 1.f);
  }
}

__global__ void score_kernel(const float* __restrict__ hg, const float* __restrict__ sw1,
                             const float* __restrict__ sb1, const float* __restrict__ sw2,
                             const float* __restrict__ sb2, int B, float* __restrict__ out){
  int g = blockIdx.x * blockDim.x + threadIdx.x;
  if (g >= B) return;
  float hvec[32];
  const float4* hp = (const float4*)(hg + g * 32);
  #pragma unroll
  for (int q = 0; q < 8; ++q){
    float4 v = hp[q];
    hvec[4*q+0] = v.x; hvec[4*q+1] = v.y; hvec[4*q+2] = v.z; hvec[4*q+3] = v.w;
  }
  float o = sb2[0];
  #pragma unroll
  for (int j = 0; j < 32; ++j){
    float a = sb1[j];
    #pragma unroll
    for (int k = 0; k < 32; ++k) a += hvec[k] * sw1[k*32 + j];
    o += fmaxf(a, 0.f) * sw2[j];
  }
  out[g] = o;
}

extern "C" void kernel_launch(void* const* d_in, const int* in_sizes, int n_in,
                              void* d_out, int out_size, void* d_ws, size_t ws_size,
                              hipStream_t stream)
{
  const int*   node_ids = (const int*)d_in[0];
  const int*   srcp     = (const int*)d_in[1];
  const int*   dstp     = (const int*)d_in[2];
  const int*   gid      = (const int*)d_in[3];
  const float* emb      = (const float*)d_in[4];
  const float* W0       = (const float*)d_in[5];
  const float* al0      = (const float*)d_in[6];
  const float* ar0      = (const float*)d_in[7];
  const float* b0       = (const float*)d_in[8];
  const float* W1       = (const float*)d_in[9];
  const float* al1      = (const float*)d_in[10];
  const float* ar1      = (const float*)d_in[11];
  const float* b1       = (const float*)d_in[12];
  const float* sw1      = (const float*)d_in[13];
  const float* sb1      = (const float*)d_in[14];
  const float* sw2      = (const float*)d_in[15];
  const float* sb2      = (const float*)d_in[16];

  int N = in_sizes[0];
  int E = in_sizes[1];
  int B = out_size;           // output is [B,1] float32
  float* out = (float*)d_out;

  // Workspace carve-out (256B aligned)
  char* p = (char*)d_ws;
  auto alloc = [&](size_t bytes) -> char* {
    char* r = p;
    p += (bytes + 255) & ~(size_t)255;
    return r;
  };
  // Coarse dst-buckets: one workgroup per bucket in the fill pass.
  // Constraints: nbk <= 512 (LDS hist / single-block bscan), bsz <= 4096
  // (fill LDS cursors), src fits in (32-shift) bits in the packed record.
  int shift = 9;
  while ((((long)N + (1L << shift) - 1) >> shift) > 512 && shift < 12) ++shift;
  int nbk = (int)(((long)N + (1L << shift) - 1) >> shift);

  int*      deg     = (int*)alloc((size_t)N * 4);
  int*      startv  = (int*)alloc((size_t)N * 4);
  int*      bcount  = (int*)alloc((size_t)nbk * 4);
  int*      gcur    = (int*)alloc((size_t)nbk * 4);
  int*      csr_src = (int*)alloc((size_t)E * 4);
  float*    el      = (float*)alloc((size_t)N * 16);
  float*    er      = (float*)alloc((size_t)N * 16);
  size_t fbytes  = (size_t)N * 128;
  size_t ebytes  = (size_t)E * 4;
  float*    f       = (float*)alloc(fbytes > ebytes ? fbytes : ebytes);
  float*    h       = (float*)alloc((size_t)N * 128);
  float*    hg      = (float*)alloc((size_t)B * 32 * 4);
  unsigned* ebuf    = (unsigned*)f;  // disjoint lifetime: consumed before fc writes f

  hipMemsetAsync(bcount, 0, (size_t)nbk * 4, stream);

  int eb4k = (E + 4095) / 4096;
  bhist_kernel<<<eb4k, 256, 0, stream>>>(dstp, E, shift, nbk, bcount);
  bscan_kernel<<<1, 512, 0, stream>>>(bcount, nbk, gcur);
  bin_kernel<<<eb4k, 256, 0, stream>>>(srcp, dstp, E, shift, nbk, gcur, ebuf);
  // after bin: gcur[b] == end offset of bucket b
  fill_csr4_kernel<<<nbk, 512, 0, stream>>>(ebuf, gcur, shift, N, startv, deg, csr_src);

  int nblk = (N + 255) / 256;
  int ablk = (N + 3) / 4;
  // Layer 0: h_in = emb[node_ids]
  fc_kernel<<<nblk, 256, 0, stream>>>(emb, node_ids, W0, al0, ar0, N, f, el, er);
  gat_agg_kernel<<<ablk, 256, 0, stream>>>(csr_src, startv, deg, f, el, er, b0, N, h);
  // Layer 1: h_in = h
  fc_kernel<<<nblk, 256, 0, stream>>>(h, nullptr, W1, al1, ar1, N, f, el, er);
  gat_agg_kernel<<<ablk, 256, 0, stream>>>(csr_src, startv, deg, f, el, er, b1, N, h);

  pool_kernel<<<B, 256, 0, stream>>>(h, gid, N, hg);
  score_kernel<<<(B + 63) / 64, 64, 0, stream>>>(hg, sw1, sb1, sw2, sb2, B, out);
}

// Round 7
// 445.693 us; speedup vs baseline: 2.1776x; 1.0170x over previous
//
#include <hip/hip_runtime.h>
#include <hip/hip_fp16.h>
#include <math.h>

__device__ __forceinline__ float lrelu(float x){ return x > 0.f ? x : 0.2f * x; }

// Per-block LDS histogram of dst-buckets -> few global atomics per block.
__global__ __launch_bounds__(256) void bhist_kernel(
    const int* __restrict__ dst, int E, int shift, int nbk, int* __restrict__ bcount)
{
  __shared__ int hist[512];
  int t = threadIdx.x;
  for (int i = t; i < nbk; i += 256) hist[i] = 0;
  __syncthreads();
  long base = (long)blockIdx.x * 4096;
  #pragma unroll
  for (int k = 0; k < 16; ++k){
    long e = base + (long)k * 256 + t;
    if (e < E) atomicAdd(&hist[dst[e] >> shift], 1);
  }
  __syncthreads();
  for (int i = t; i < nbk; i += 256){
    int v = hist[i];
    if (v) atomicAdd(&bcount[i], v);
  }
}

// Single-block exclusive scan of bucket counts -> bucket start cursors.
__global__ __launch_bounds__(512) void bscan_kernel(
    const int* __restrict__ bcount, int nbk, int* __restrict__ gcur)
{
  __shared__ int sh[512];
  int t = threadIdx.x;
  int v = (t < nbk) ? bcount[t] : 0;
  sh[t] = v; __syncthreads();
  for (int off = 1; off < 512; off <<= 1){
    int x = (t >= off) ? sh[t - off] : 0;
    __syncthreads();
    sh[t] += x;
    __syncthreads();
  }
  if (t < nbk) gcur[t] = sh[t] - v;   // exclusive bucket start
}

// Bin edges by coarse dst-bucket (packed u32: src<<shift | local_dst).
// After this kernel, gcur[b] == END offset of bucket b's edge range.
__global__ __launch_bounds__(256) void bin_kernel(
    const int* __restrict__ src, const int* __restrict__ dst, int E, int shift, int nbk,
    int* __restrict__ gcur, unsigned* __restrict__ ebuf)
{
  __shared__ int hist[512];
  __shared__ int lbase[512];
  int t = threadIdx.x;
  int mask = (1 << shift) - 1;
  long base = (long)blockIdx.x * 4096;
  for (int i = t; i < nbk; i += 256) hist[i] = 0;
  __syncthreads();
  int s_[16], d_[16];
  #pragma unroll
  for (int k = 0; k < 16; ++k){
    long e = base + (long)k * 256 + t;
    if (e < E){
      s_[k] = src[e]; d_[k] = dst[e];
      atomicAdd(&hist[d_[k] >> shift], 1);
    } else d_[k] = -1;
  }
  __syncthreads();
  for (int i = t; i < nbk; i += 256){
    lbase[i] = atomicAdd(&gcur[i], hist[i]);
    hist[i] = 0;
  }
  __syncthreads();
  #pragma unroll
  for (int k = 0; k < 16; ++k){
    if (d_[k] >= 0){
      int b = d_[k] >> shift;
      int r = atomicAdd(&hist[b], 1);
      ebuf[lbase[b] + r] = ((unsigned)s_[k] << shift) | (unsigned)(d_[k] & mask);
    }
  }
}

// One workgroup OWNS one bucket: LDS per-node degree histogram -> block-local
// exclusive scan -> coalesced atomic-free startv/deg writes -> LDS-cursor CSR
// placement. Bucket's csr window written by a single CU (full-line writeback).
__global__ __launch_bounds__(512) void fill_csr4_kernel(
    const unsigned* __restrict__ ebuf, const int* __restrict__ bend,
    int shift, int N, int* __restrict__ startv, int* __restrict__ deg,
    int* __restrict__ csr_src)
{
  __shared__ int cnt[4096];               // supports shift <= 12
  __shared__ int psum[512];
  int b = blockIdx.x;
  int t = threadIdx.x;
  int bsz = 1 << shift;
  int mask = bsz - 1;
  int nbase = b << shift;
  for (int i = t; i < bsz; i += 512) cnt[i] = 0;
  __syncthreads();
  int gs = (b == 0) ? 0 : bend[b - 1];
  int ge = bend[b];
  for (int e = gs + t; e < ge; e += 512)
    atomicAdd(&cnt[ebuf[e] & mask], 1);
  __syncthreads();
  // two-level exclusive scan over cnt[0..bsz)
  int k = bsz >> 9;                       // elems per thread (>=1)
  int base = t * k;
  int loc = 0;
  for (int j = 0; j < k; ++j) loc += cnt[base + j];
  psum[t] = loc;
  __syncthreads();
  for (int off = 1; off < 512; off <<= 1){
    int x = (t >= off) ? psum[t - off] : 0;
    __syncthreads();
    psum[t] += x;
    __syncthreads();
  }
  int run = gs + psum[t] - loc;           // global exclusive prefix for chunk
  for (int j = 0; j < k; ++j){
    int node = nbase + base + j;
    int c = cnt[base + j];
    cnt[base + j] = run;                  // becomes placement cursor
    if (node < N){ startv[node] = run; deg[node] = c; }
    run += c;
  }
  __syncthreads();
  for (int e = gs + t; e < ge; e += 512){
    unsigned v = ebuf[e];
    int slot = atomicAdd(&cnt[v & mask], 1);
    csr_src[slot] = (int)(v >> shift);
  }
}

// f = h @ W (32x32) stored as FP16 (64B/row -> 1 cache line per edge gather),
// el/er = per-head dot with al/ar in fp32. One thread per node.
__global__ __launch_bounds__(256) void fc_kernel(
    const float* __restrict__ hin, const int* __restrict__ nid,
    const float* __restrict__ W, const float* __restrict__ al, const float* __restrict__ ar,
    int n, __half* __restrict__ fh, float* __restrict__ el, float* __restrict__ er)
{
  __shared__ __align__(16) float Ws[1024];
  __shared__ float als[32], ars[32];
  int t = threadIdx.x;
  for (int i = t; i < 1024; i += 256) Ws[i] = W[i];
  if (t < 32){ als[t] = al[t]; ars[t] = ar[t]; }
  __syncthreads();
  int i = blockIdx.x * 256 + t;
  if (i >= n) return;
  long row = nid ? (long)nid[i] : (long)i;
  const float4* hp = (const float4*)(hin + row * 32);
  float h[32];
  #pragma unroll
  for (int q = 0; q < 8; ++q){
    float4 v = hp[q];
    h[4*q+0] = v.x; h[4*q+1] = v.y; h[4*q+2] = v.z; h[4*q+3] = v.w;
  }
  float fv[32];
  #pragma unroll
  for (int j = 0; j < 32; j += 4){
    float ax = 0.f, ay = 0.f, az = 0.f, aw = 0.f;
    #pragma unroll
    for (int k = 0; k < 32; ++k){
      float hk = h[k];
      float4 w = *(const float4*)&Ws[k*32 + j];
      ax += hk * w.x; ay += hk * w.y; az += hk * w.z; aw += hk * w.w;
    }
    fv[j] = ax; fv[j+1] = ay; fv[j+2] = az; fv[j+3] = aw;
  }
  __half hrow[32];
  #pragma unroll
  for (int j = 0; j < 32; ++j) hrow[j] = __float2half_rn(fv[j]);
  float4* fp = (float4*)(fh + (size_t)i * 32);
  #pragma unroll
  for (int q = 0; q < 4; ++q) fp[q] = ((const float4*)hrow)[q];
  float elv[4], erv[4];
  #pragma unroll
  for (int hh = 0; hh < 4; ++hh){
    float a = 0.f, b = 0.f;
    #pragma unroll
    for (int d = 0; d < 8; ++d){
      a += fv[hh*8 + d] * als[hh*8 + d];
      b += fv[hh*8 + d] * ars[hh*8 + d];
    }
    elv[hh] = a; erv[hh] = b;
  }
  *(float4*)(el + (size_t)i * 4) = make_float4(elv[0], elv[1], elv[2], elv[3]);
  *(float4*)(er + (size_t)i * 4) = make_float4(erv[0], erv[1], erv[2], erv[3]);
}

// One wave per dst node. Fast path (deg<=64):
//  - per-lane edge: ex = exp(lrelu(el+er)) raw in LDS (softmax shift-invariant;
//    activations O(0.1), no overflow); normalize once in epilogue
//  - gather: 8 lanes per edge, each lane reads 4 fp16 cols (8B) -> 64B/edge,
//    converts to fp32 and FMAs; 8 edges in flight
__global__ __launch_bounds__(256) void gat_agg_kernel(
    const int* __restrict__ csr_src, const int* __restrict__ startv, const int* __restrict__ deg,
    const __half* __restrict__ fh, const float* __restrict__ el, const float* __restrict__ er,
    const float* __restrict__ bias, int n, float* __restrict__ hout)
{
  __shared__ int    su_s[4][64];
  __shared__ float4 ex_s[4][64];
  int wid  = threadIdx.x >> 6;
  int lane = threadIdx.x & 63;
  int v = blockIdx.x * 4 + wid;
  if (v >= n) return;
  int s = startv[v];
  int d = deg[v];
  float4 er4 = *(const float4*)(er + (size_t)v * 4);

  int cq    = lane & 7;    // col-quad: cols 4cq..4cq+3
  int g     = lane >> 3;   // edge group 0..7
  int headq = cq >> 1;     // head of this col-quad

  if (d > 64){
    // slow path: 3-pass global recompute (statistically never for Poisson(16))
    int col  = lane & 31;
    int half = lane >> 5;
    int head = col >> 3;
    float m0 = -1e30f, m1 = -1e30f, m2 = -1e30f, m3 = -1e30f;
    for (int i = lane; i < d; i += 64){
      int u = csr_src[s + i];
      float4 e4 = *(const float4*)(el + (size_t)u * 4);
      m0 = fmaxf(m0, lrelu(e4.x + er4.x));
      m1 = fmaxf(m1, lrelu(e4.y + er4.y));
      m2 = fmaxf(m2, lrelu(e4.z + er4.z));
      m3 = fmaxf(m3, lrelu(e4.w + er4.w));
    }
    #pragma unroll
    for (int off = 32; off >= 1; off >>= 1){
      m0 = fmaxf(m0, __shfl_xor(m0, off));
      m1 = fmaxf(m1, __shfl_xor(m1, off));
      m2 = fmaxf(m2, __shfl_xor(m2, off));
      m3 = fmaxf(m3, __shfl_xor(m3, off));
    }
    float s0 = 0.f, s1 = 0.f, s2 = 0.f, s3 = 0.f;
    for (int i = lane; i < d; i += 64){
      int u = csr_src[s + i];
      float4 e4 = *(const float4*)(el + (size_t)u * 4);
      s0 += expf(lrelu(e4.x + er4.x) - m0);
      s1 += expf(lrelu(e4.y + er4.y) - m1);
      s2 += expf(lrelu(e4.z + er4.z) - m2);
      s3 += expf(lrelu(e4.w + er4.w) - m3);
    }
    #pragma unroll
    for (int off = 32; off >= 1; off >>= 1){
      s0 += __shfl_xor(s0, off);
      s1 += __shfl_xor(s1, off);
      s2 += __shfl_xor(s2, off);
      s3 += __shfl_xor(s3, off);
    }
    float me  = head == 0 ? m0 : head == 1 ? m1 : head == 2 ? m2 : m3;
    float se  = head == 0 ? s0 : head == 1 ? s1 : head == 2 ? s2 : s3;
    float re  = 1.f / se;
    float ere = head == 0 ? er4.x : head == 1 ? er4.y : head == 2 ? er4.z : er4.w;
    float acc = 0.f;
    for (int i = half; i < d; i += 2){
      int u = csr_src[s + i];
      float e = lrelu(el[(size_t)u * 4 + head] + ere);
      float alpha = expf(e - me) * re;
      acc = fmaf(alpha, __half2float(fh[(size_t)u * 32 + col]), acc);
    }
    acc += __shfl_xor(acc, 32);
    if (lane < 32){
      float o = acc + bias[col];
      hout[(size_t)v * 32 + col] = fmaxf(o, 0.f);
    }
    return;
  }

  float4 o4 = make_float4(0.f, 0.f, 0.f, 0.f);
  float s0 = 0.f, s1 = 0.f, s2 = 0.f, s3 = 0.f;
  if (d > 0){
    int*    suw = su_s[wid];
    float4* exw = ex_s[wid];
    float x0 = 0.f, x1 = 0.f, x2 = 0.f, x3 = 0.f;
    if (lane < d){
      int u = csr_src[s + lane];
      suw[lane] = u;
      float4 l4 = *(const float4*)(el + (size_t)u * 4);
      x0 = __expf(lrelu(l4.x + er4.x));
      x1 = __expf(lrelu(l4.y + er4.y));
      x2 = __expf(lrelu(l4.z + er4.z));
      x3 = __expf(lrelu(l4.w + er4.w));
      exw[lane] = make_float4(x0, x1, x2, x3);
    }
    s0 = x0; s1 = x1; s2 = x2; s3 = x3;
    #pragma unroll
    for (int off = 32; off >= 1; off >>= 1){
      s0 += __shfl_xor(s0, off);
      s1 += __shfl_xor(s1, off);
      s2 += __shfl_xor(s2, off);
      s3 += __shfl_xor(s3, off);
    }
    // DS ops of a wave complete in order; stop compiler reordering and drain
    // LDS before cross-lane reads. Wave-local data: no block barrier needed.
    asm volatile("s_waitcnt lgkmcnt(0)" ::: "memory");
    const float* exf = (const float*)exw;
    for (int i = g; i < d; i += 8){
      int u = suw[i];
      float a = exf[i * 4 + headq];
      uint2 raw = *(const uint2*)(fh + ((size_t)u << 5) + (cq << 2));
      float2 f01 = __half22float2(*(const __half2*)&raw.x);
      float2 f23 = __half22float2(*(const __half2*)&raw.y);
      o4.x = fmaf(a, f01.x, o4.x);
      o4.y = fmaf(a, f01.y, o4.y);
      o4.z = fmaf(a, f23.x, o4.z);
      o4.w = fmaf(a, f23.y, o4.w);
    }
    #pragma unroll
    for (int off = 32; off >= 8; off >>= 1){
      o4.x += __shfl_xor(o4.x, off);
      o4.y += __shfl_xor(o4.y, off);
      o4.z += __shfl_xor(o4.z, off);
      o4.w += __shfl_xor(o4.w, off);
    }
  }
  if (lane < 8){
    float se = headq == 0 ? s0 : headq == 1 ? s1 : headq == 2 ? s2 : s3;
    float rs = (d > 0) ? 1.f / se : 0.f;
    float4 b4 = *(const float4*)(bias + cq * 4);
    float4 r;
    r.x = fmaxf(fmaf(o4.x, rs, b4.x), 0.f);
    r.y = fmaxf(fmaf(o4.y, rs, b4.y), 0.f);
    r.z = fmaxf(fmaf(o4.z, rs, b4.z), 0.f);
    r.w = fmaxf(fmaf(o4.w, rs, b4.w), 0.f);
    *(float4*)(hout + (size_t)v * 32 + cq * 4) = r;
  }
}

__device__ int lower_bound_dev(const int* a, int n, int key){
  int lo = 0, hi = n;
  while (lo < hi){
    int mid = (lo + hi) >> 1;
    if (a[mid] < key) lo = mid + 1; else hi = mid;
  }
  return lo;
}

__global__ void pool_kernel(const float* __restrict__ hout, const int* __restrict__ gid,
                            int n, float* __restrict__ hg){
  __shared__ int lohi[2];
  int g = blockIdx.x;
  int t = threadIdx.x;
  if (t < 2) lohi[t] = lower_bound_dev(gid, n, g + t);
  __syncthreads();
  int lo = lohi[0], hi = lohi[1];
  int cnt = hi - lo;
  int col = t & 31, r0 = t >> 5;
  float acc = 0.f;
  for (int r = r0; r < cnt; r += 8)
    acc += hout[(size_t)(lo + r) * 32 + col];
  __shared__ float red[256];
  red[t] = acc; __syncthreads();
  if (t < 128) red[t] += red[t + 128];
  __syncthreads();
  if (t < 64) red[t] += red[t + 64];
  __syncthreads();
  if (t < 32){
    float sum = red[t] + red[t + 32];
    hg[g * 32 + t] = sum / fmaxf((float)cnt, 1.f);
  }
}

__global__ void score_kernel(const float* __restrict__ hg, const float* __restrict__ sw1,
                             const float* __restrict__ sb1, const float* __restrict__ sw2,
                             const float* __restrict__ sb2, int B, float* __restrict__ out){
  int g = blockIdx.x * blockDim.x + threadIdx.x;
  if (g >= B) return;
  float hvec[32];
  const float4* hp = (const float4*)(hg + g * 32);
  #pragma unroll
  for (int q = 0; q < 8; ++q){
    float4 v = hp[q];
    hvec[4*q+0] = v.x; hvec[4*q+1] = v.y; hvec[4*q+2] = v.z; hvec[4*q+3] = v.w;
  }
  float o = sb2[0];
  #pragma unroll
  for (int j = 0; j < 32; ++j){
    float a = sb1[j];
    #pragma unroll
    for (int k = 0; k < 32; ++k) a += hvec[k] * sw1[k*32 + j];
    o += fmaxf(a, 0.f) * sw2[j];
  }
  out[g] = o;
}

extern "C" void kernel_launch(void* const* d_in, const int* in_sizes, int n_in,
                              void* d_out, int out_size, void* d_ws, size_t ws_size,
                              hipStream_t stream)
{
  const int*   node_ids = (const int*)d_in[0];
  const int*   srcp     = (const int*)d_in[1];
  const int*   dstp     = (const int*)d_in[2];
  const int*   gid      = (const int*)d_in[3];
  const float* emb      = (const float*)d_in[4];
  const float* W0       = (const float*)d_in[5];
  const float* al0      = (const float*)d_in[6];
  const float* ar0      = (const float*)d_in[7];
  const float* b0       = (const float*)d_in[8];
  const float* W1       = (const float*)d_in[9];
  const float* al1      = (const float*)d_in[10];
  const float* ar1      = (const float*)d_in[11];
  const float* b1       = (const float*)d_in[12];
  const float* sw1      = (const float*)d_in[13];
  const float* sb1      = (const float*)d_in[14];
  const float* sw2      = (const float*)d_in[15];
  const float* sb2      = (const float*)d_in[16];

  int N = in_sizes[0];
  int E = in_sizes[1];
  int B = out_size;           // output is [B,1] float32
  float* out = (float*)d_out;

  // Workspace carve-out (256B aligned)
  char* p = (char*)d_ws;
  auto alloc = [&](size_t bytes) -> char* {
    char* r = p;
    p += (bytes + 255) & ~(size_t)255;
    return r;
  };
  // Coarse dst-buckets: one workgroup per bucket in the fill pass.
  // Constraints: nbk <= 512 (LDS hist / single-block bscan), bsz <= 4096
  // (fill LDS cursors), src fits in (32-shift) bits in the packed record.
  int shift = 9;
  while ((((long)N + (1L << shift) - 1) >> shift) > 512 && shift < 12) ++shift;
  int nbk = (int)(((long)N + (1L << shift) - 1) >> shift);

  int*      deg     = (int*)alloc((size_t)N * 4);
  int*      startv  = (int*)alloc((size_t)N * 4);
  int*      bcount  = (int*)alloc((size_t)nbk * 4);
  int*      gcur    = (int*)alloc((size_t)nbk * 4);
  int*      csr_src = (int*)alloc((size_t)E * 4);
  float*    el      = (float*)alloc((size_t)N * 16);
  float*    er      = (float*)alloc((size_t)N * 16);
  size_t fbytes  = (size_t)N * 64;          // fp16 f rows
  size_t ebytes  = (size_t)E * 4;
  __half*   fh      = (__half*)alloc(fbytes > ebytes ? fbytes : ebytes);
  float*    h       = (float*)alloc((size_t)N * 128);
  float*    hg      = (float*)alloc((size_t)B * 32 * 4);
  unsigned* ebuf    = (unsigned*)fh;  // disjoint lifetime: consumed before fc writes fh

  hipMemsetAsync(bcount, 0, (size_t)nbk * 4, stream);

  int eb4k = (E + 4095) / 4096;
  bhist_kernel<<<eb4k, 256, 0, stream>>>(dstp, E, shift, nbk, bcount);
  bscan_kernel<<<1, 512, 0, stream>>>(bcount, nbk, gcur);
  bin_kernel<<<eb4k, 256, 0, stream>>>(srcp, dstp, E, shift, nbk, gcur, ebuf);
  // after bin: gcur[b] == end offset of bucket b
  fill_csr4_kernel<<<nbk, 512, 0, stream>>>(ebuf, gcur, shift, N, startv, deg, csr_src);

  int nblk = (N + 255) / 256;
  int ablk = (N + 3) / 4;
  // Layer 0: h_in = emb[node_ids]
  fc_kernel<<<nblk, 256, 0, stream>>>(emb, node_ids, W0, al0, ar0, N, fh, el, er);
  gat_agg_kernel<<<ablk, 256, 0, stream>>>(csr_src, startv, deg, fh, el, er, b0, N, h);
  // Layer 1: h_in = h
  fc_kernel<<<nblk, 256, 0, stream>>>(h, nullptr, W1, al1, ar1, N, fh, el, er);
  gat_agg_kernel<<<ablk, 256, 0, stream>>>(csr_src, startv, deg, fh, el, er, b1, N, h);

  pool_kernel<<<B, 256, 0, stream>>>(h, gid, N, hg);
  score_kernel<<<(B + 63) / 64, 64, 0, stream>>>(hg, sw1, sb1, sw2, sb2, B, out);
}